// Round 4
// baseline (1797.061 us; speedup 1.0000x reference)
//
#include <hip/hip_runtime.h>
#include <hip/hip_bf16.h>
#include <math.h>

typedef __hip_bfloat16  bf16;
typedef __hip_bfloat162 bf162;

#define BB   2
#define CINC 64
#define CAC  128
#define NN   1024
#define SSS  32

// ---- workspace layout (float offsets) ----
#define OFF_KT   0        // Wk2^T  [c(64)][i(128)]
#define OFF_VT   8192     // Wv2^T
#define OFF_QT   16384    // Wq2^T
#define OFF_WR   24576    // w_r [128]
#define OFF_WE21 24704    // We2@We1 [o(128)][c(64)]
#define WS_BASE_FLOATS 32896
#define OFF_F1T  32896    // Wf1^T [c(384)][o(128)]
#define OFF_F2T  82048    // Wf2^T [c(128)][o(128)]
#define WS_FULL_FLOATS 98432

// ---- shared memory layout (BYTE offsets) ----
// s_att bf16 [128][100] (96 used, stride 100 for bank spread).
// s_h / s_a (bf16 [128][38]) alias into s_att (dead after Phase E reads).
// s_scr holds z0 (f32 288, phases C/D) then red (f32 384, phase H).
#define S_ATT_B 0        // bf16[128][100] = 25600 B
#define S_H_B   0        // alias bf16[128][38] = 9728 B
#define S_A_B   9728     // alias bf16[128][38]
#define S_SCR_B 25600    // f32[384]
#define S_Q_B   27136    // f32[128*3]
#define S_XYZ_B 28672    // f32[96]
#define S_FT0_B 29056    // f32[192]
#define SMEM_BYTES 29824  // -> 5 blocks/CU (149120 <= 163840)

// ---------- prep kernel 1: We21 = W_e2 @ W_e1 ----------
__global__ __launch_bounds__(256) void prep1(const float* __restrict__ We1,
                                             const float* __restrict__ We2,
                                             float* __restrict__ ws) {
    int e = blockIdx.x * 256 + threadIdx.x;   // 8192 entries, grid = 32
    int o = e >> 6, c = e & 63;
    float acc = 0.f;
    for (int m = 0; m < 128; ++m)
        acc = fmaf(We2[o * 128 + m], We1[m * 64 + c], acc);
    ws[OFF_WE21 + o * 64 + c] = acc;
}

// ---------- prep kernel 2: fused weights + transposes ----------
__global__ __launch_bounds__(256) void prep2(const float* __restrict__ Wq,
                                             const float* __restrict__ Wk,
                                             const float* __restrict__ Wv,
                                             const float* __restrict__ Wr1,
                                             const float* __restrict__ Wr2,
                                             const float* __restrict__ Wf1,
                                             const float* __restrict__ Wf2,
                                             float* __restrict__ ws, int use_t) {
    const float* we21 = ws + OFF_WE21;
    int e = blockIdx.x * 256 + threadIdx.x;
    if (e < 24576) {
        const float* W = (e < 8192) ? Wk : (e < 16384) ? Wv : Wq;
        float* dst = ws + ((e < 8192) ? OFF_KT : (e < 16384) ? OFF_VT : OFF_QT);
        int le = e & 8191;
        int i = le >> 6, c = le & 63;
        float acc = 0.f;
        for (int o = 0; o < 128; ++o)
            acc = fmaf(W[i * 128 + o], we21[o * 64 + c], acc);
        dst[c * 128 + i] = acc;
    } else if (e < 24704) {
        int i = e - 24576;
        float acc = 0.f;
        for (int m = 0; m < 64; ++m)
            acc = fmaf(Wr2[i * 64 + m], Wr1[m], acc);
        ws[OFF_WR + i] = acc;
    } else if (use_t) {
        if (e < 24704 + 49152) {
            int f = e - 24704;
            int c = f >> 7, o = f & 127;
            ws[OFF_F1T + f] = Wf1[o * 384 + c];
        } else if (e < 24704 + 49152 + 16384) {
            int f = e - (24704 + 49152);
            int c = f >> 7, o = f & 127;
            ws[OFF_F2T + c * 128 + o] = Wf2[o * 128 + c];
        }
    }
}

// ---------- main fused kernel: one block per (b, n), 5 blocks/CU ----------
__global__ __launch_bounds__(256, 5) void fused_main(
        const float* __restrict__ gxyz, const float* __restrict__ gfts,
        const float* __restrict__ qxyz, const float* __restrict__ Wstd,
        const float* __restrict__ Wf1,  const float* __restrict__ bf1,
        const float* __restrict__ Wf2,  const float* __restrict__ bf2,
        const float* __restrict__ ws,   float* __restrict__ out, int use_t) {
    extern __shared__ char smc[];
    bf16*  s_att = (bf16*)(smc + S_ATT_B);   // [128][100]
    bf16*  s_h   = (bf16*)(smc + S_H_B);     // alias [128][38]
    bf16*  s_a   = (bf16*)(smc + S_A_B);     // alias [128][38]
    float* s_scr = (float*)(smc + S_SCR_B);  // z0 (C/D) then red (H)
    float* s_q   = (float*)(smc + S_Q_B);
    float* s_xyz = (float*)(smc + S_XYZ_B);
    float* s_ft0 = (float*)(smc + S_FT0_B);

    const int t   = threadIdx.x;
    const int bid = blockIdx.x;
    const int b   = bid >> 10;
    const int n   = bid & 1023;

    const float* gb = gfts + (size_t)b * (CINC * 3 * NN * SSS) + n * SSS;

    // ---------- Phase A: stage fts s=0 columns + xyz_rel ----------
    if (t < 192) s_ft0[t] = gb[(size_t)t * (NN * SSS)];   // [c*3+d] at s=0
    if (t >= 160) {
        int id = t - 160;                // 0..95
        int d = id >> 5, s = id & 31;
        s_xyz[id] = gxyz[((b * NN + n) * SSS + s) * 3 + d] - qxyz[(b * NN + n) * 3 + d];
    }
    __syncthreads();

    // ---------- Phase A2: q[i][d] from s=0 columns ----------
    if (t < 128) {
        const float* qtw = ws + OFF_QT;
        float q0 = 0.f, q1 = 0.f, q2 = 0.f;
        for (int c = 0; c < 64; ++c) {
            float w = qtw[c * 128 + t];
            q0 = fmaf(w, s_ft0[c * 3 + 0], q0);
            q1 = fmaf(w, s_ft0[c * 3 + 1], q1);
            q2 = fmaf(w, s_ft0[c * 3 + 2], q2);
        }
        s_q[t * 3 + 0] = q0; s_q[t * 3 + 1] = q1; s_q[t * 3 + 2] = q2;
    }
    __syncthreads();

    // ---------- Phase B: k,v = Wk2/Wv2 @ fts, fts direct from global ----------
    const int ib = (t >> 3) << 2;    // 0..124
    const int mb = (t & 7) * 12;     // 0..84
    int offm[3];
    #pragma unroll
    for (int q = 0; q < 3; ++q) {
        int m4 = mb + 4 * q;
        offm[q] = (m4 >> 5) * (NN * SSS) + (m4 & 31);
    }
    float ka[4][12], va[4][12];
    #pragma unroll
    for (int r = 0; r < 4; ++r)
        #pragma unroll
        for (int j = 0; j < 12; ++j) { ka[r][j] = 0.f; va[r][j] = 0.f; }
    {
        const float* kt = ws + OFF_KT;
        const float* vt = ws + OFF_VT;
        #pragma unroll 2
        for (int c = 0; c < 64; ++c) {
            const float* fb = gb + c * (3 * NN * SSS);
            float4 f0 = *(const float4*)(fb + offm[0]);
            float4 f1 = *(const float4*)(fb + offm[1]);
            float4 f2 = *(const float4*)(fb + offm[2]);
            float4 wk = *(const float4*)(kt + c * 128 + ib);
            float4 wv = *(const float4*)(vt + c * 128 + ib);
            float f[12]  = {f0.x, f0.y, f0.z, f0.w, f1.x, f1.y, f1.z, f1.w,
                            f2.x, f2.y, f2.z, f2.w};
            float wks[4] = {wk.x, wk.y, wk.z, wk.w};
            float wvs[4] = {wv.x, wv.y, wv.z, wv.w};
            #pragma unroll
            for (int r = 0; r < 4; ++r)
                #pragma unroll
                for (int j = 0; j < 12; ++j) {
                    ka[r][j] = fmaf(wks[r], f[j], ka[r][j]);
                    va[r][j] = fmaf(wvs[r], f[j], va[r][j]);
                }
        }
    }
    // Phase B-post: attn = q - k + pos (-> bf16 LDS); v' = v + pos (registers)
    {
        float4 wr4 = *(const float4*)(ws + OFF_WR + ib);
        float wrs[4] = {wr4.x, wr4.y, wr4.z, wr4.w};
        #pragma unroll
        for (int r = 0; r < 4; ++r) {
            int i = ib + r;
            float qv[3] = {s_q[i * 3 + 0], s_q[i * 3 + 1], s_q[i * 3 + 2]};
            float av[12];
            #pragma unroll
            for (int j = 0; j < 12; ++j) {
                int m = mb + j;
                int d = m >> 5;
                float pos = wrs[r] * s_xyz[m];
                av[j] = qv[d] - ka[r][j] + pos;
                va[r][j] += pos;
            }
            bf16* ap = s_att + i * 100 + mb;     // mb even -> 4B aligned
            #pragma unroll
            for (int u = 0; u < 6; ++u)
                *(bf162*)(ap + 2 * u) =
                    __float22bfloat162_rn(make_float2(av[2 * u], av[2 * u + 1]));
        }
    }
    __syncthreads();

    // ---------- Phase C: z0[j][kk][s] = sum_i Wstd[j][i] * attn[i][kk][s] ----------
    if (t < 144) {
        int j  = t / 48;
        int rp = (t - j * 48) * 2;       // even rem in [0,96)
        const float* wrow = Wstd + j * 128;
        float acc0 = 0.f, acc1 = 0.f;
        for (int i = 0; i < 128; ++i) {
            float2 a2 = __bfloat1622float2(*(const bf162*)(s_att + i * 100 + rp));
            float w = wrow[i];
            acc0 = fmaf(w, a2.x, acc0);
            acc1 = fmaf(w, a2.y, acc1);
        }
        s_scr[j * 96 + rp]     = acc0;   // z0: layout j*96 + kk*32 + s
        s_scr[j * 96 + rp + 1] = acc1;
    }
    __syncthreads();

    // ---------- Phase D: attn2[i][kk][s] = sum_j attn[i][j][s]*z0[j][kk][s] ----------
    for (int e = t; e < 2048; e += 256) {
        int i  = e >> 4;
        int sp = (e & 15) * 2;           // even s
        float2 a0 = __bfloat1622float2(*(const bf162*)(s_att + i * 100 + sp));
        float2 a1 = __bfloat1622float2(*(const bf162*)(s_att + i * 100 + 32 + sp));
        float2 a2 = __bfloat1622float2(*(const bf162*)(s_att + i * 100 + 64 + sp));
        #pragma unroll
        for (int kk = 0; kk < 3; ++kk) {
            float zx0 = s_scr[0 * 96 + kk * 32 + sp], zx1 = s_scr[0 * 96 + kk * 32 + sp + 1];
            float zy0 = s_scr[1 * 96 + kk * 32 + sp], zy1 = s_scr[1 * 96 + kk * 32 + sp + 1];
            float zz0 = s_scr[2 * 96 + kk * 32 + sp], zz1 = s_scr[2 * 96 + kk * 32 + sp + 1];
            float x = a0.x * zx0 + a1.x * zy0 + a2.x * zz0;
            float y = a0.y * zx1 + a1.y * zy1 + a2.y * zz1;
            *(bf162*)(s_att + i * 100 + kk * 32 + sp) =
                __float22bfloat162_rn(make_float2(x, y));
        }
    }
    __syncthreads();

    // ---------- Phase E: h = relu(Wf1 @ attn2 + b_f1)  (4o x 4s tiles) ----------
    const int ob = (t >> 3) << 2;
    const int sb = (t & 7) << 2;
    {
        float hacc[4][4];
        #pragma unroll
        for (int r = 0; r < 4; ++r)
            #pragma unroll
            for (int x = 0; x < 4; ++x) hacc[r][x] = 0.f;
        if (use_t) {
            const float* f1t = ws + OFF_F1T;
            for (int i = 0; i < 128; ++i) {
                #pragma unroll
                for (int kk = 0; kk < 3; ++kk) {
                    float2 p0 = __bfloat1622float2(*(const bf162*)(s_att + i * 100 + kk * 32 + sb));
                    float2 p1 = __bfloat1622float2(*(const bf162*)(s_att + i * 100 + kk * 32 + sb + 2));
                    float4 w4 = *(const float4*)(f1t + (i * 3 + kk) * 128 + ob);
                    float av[4] = {p0.x, p0.y, p1.x, p1.y};
                    float w[4]  = {w4.x, w4.y, w4.z, w4.w};
                    #pragma unroll
                    for (int r = 0; r < 4; ++r)
                        #pragma unroll
                        for (int x = 0; x < 4; ++x)
                            hacc[r][x] = fmaf(w[r], av[x], hacc[r][x]);
                }
            }
        } else {
            for (int i = 0; i < 128; ++i) {
                #pragma unroll
                for (int kk = 0; kk < 3; ++kk) {
                    float2 p0 = __bfloat1622float2(*(const bf162*)(s_att + i * 100 + kk * 32 + sb));
                    float2 p1 = __bfloat1622float2(*(const bf162*)(s_att + i * 100 + kk * 32 + sb + 2));
                    float av[4] = {p0.x, p0.y, p1.x, p1.y};
                    int c = i * 3 + kk;
                    float w[4];
                    #pragma unroll
                    for (int r = 0; r < 4; ++r) w[r] = Wf1[(ob + r) * 384 + c];
                    #pragma unroll
                    for (int r = 0; r < 4; ++r)
                        #pragma unroll
                        for (int x = 0; x < 4; ++x)
                            hacc[r][x] = fmaf(w[r], av[x], hacc[r][x]);
                }
            }
        }
        // s_att fully consumed; barrier, then write h into the aliased region
        __syncthreads();
        #pragma unroll
        for (int r = 0; r < 4; ++r) {
            float bias = bf1[ob + r];
            float h0 = fmaxf(hacc[r][0] + bias, 0.f);
            float h1 = fmaxf(hacc[r][1] + bias, 0.f);
            float h2 = fmaxf(hacc[r][2] + bias, 0.f);
            float h3 = fmaxf(hacc[r][3] + bias, 0.f);
            bf16* hp = s_h + (ob + r) * 38 + sb;
            *(bf162*)(hp)     = __float22bfloat162_rn(make_float2(h0, h1));
            *(bf162*)(hp + 2) = __float22bfloat162_rn(make_float2(h2, h3));
        }
    }
    __syncthreads();

    // ---------- Phase F: logits a = Wf2 @ h + b_f2 ----------
    {
        float facc[4][4];
        #pragma unroll
        for (int r = 0; r < 4; ++r)
            #pragma unroll
            for (int x = 0; x < 4; ++x) facc[r][x] = 0.f;
        if (use_t) {
            const float* f2t = ws + OFF_F2T;
            for (int c = 0; c < 128; ++c) {
                float2 p0 = __bfloat1622float2(*(const bf162*)(s_h + c * 38 + sb));
                float2 p1 = __bfloat1622float2(*(const bf162*)(s_h + c * 38 + sb + 2));
                float4 w4 = *(const float4*)(f2t + c * 128 + ob);
                float hv[4] = {p0.x, p0.y, p1.x, p1.y};
                float w[4]  = {w4.x, w4.y, w4.z, w4.w};
                #pragma unroll
                for (int r = 0; r < 4; ++r)
                    #pragma unroll
                    for (int x = 0; x < 4; ++x)
                        facc[r][x] = fmaf(w[r], hv[x], facc[r][x]);
            }
        } else {
            for (int c = 0; c < 128; ++c) {
                float2 p0 = __bfloat1622float2(*(const bf162*)(s_h + c * 38 + sb));
                float2 p1 = __bfloat1622float2(*(const bf162*)(s_h + c * 38 + sb + 2));
                float hv[4] = {p0.x, p0.y, p1.x, p1.y};
                float w[4];
                #pragma unroll
                for (int r = 0; r < 4; ++r) w[r] = Wf2[(ob + r) * 128 + c];
                #pragma unroll
                for (int r = 0; r < 4; ++r)
                    #pragma unroll
                    for (int x = 0; x < 4; ++x)
                        facc[r][x] = fmaf(w[r], hv[x], facc[r][x]);
            }
        }
        #pragma unroll
        for (int r = 0; r < 4; ++r) {
            float bias = bf2[ob + r];
            bf16* ap = s_a + (ob + r) * 38 + sb;
            *(bf162*)(ap)     = __float22bfloat162_rn(
                                    make_float2(facc[r][0] + bias, facc[r][1] + bias));
            *(bf162*)(ap + 2) = __float22bfloat162_rn(
                                    make_float2(facc[r][2] + bias, facc[r][3] + bias));
        }
    }
    __syncthreads();

    // ---------- Phase G: softmax over s (scale 1/sqrt(128)) ----------
    if (t < 128) {
        bf16* row = s_a + t * 38;
        float vals[32];
        #pragma unroll
        for (int s2 = 0; s2 < 16; ++s2) {
            float2 p = __bfloat1622float2(*(const bf162*)(row + 2 * s2));
            vals[2 * s2] = p.x; vals[2 * s2 + 1] = p.y;
        }
        float mx = -INFINITY;
        #pragma unroll
        for (int s = 0; s < 32; ++s) mx = fmaxf(mx, vals[s]);
        const float inv = 0.08838834764831845f;   // 1/sqrt(128)
        float sum = 0.f;
        #pragma unroll
        for (int s = 0; s < 32; ++s) { vals[s] = __expf((vals[s] - mx) * inv); sum += vals[s]; }
        float rs = 1.f / sum;
        #pragma unroll
        for (int s2 = 0; s2 < 16; ++s2)
            *(bf162*)(row + 2 * s2) = __float22bfloat162_rn(
                make_float2(vals[2 * s2] * rs, vals[2 * s2 + 1] * rs));
    }
    __syncthreads();

    // ---------- Phase H: resi[i][d] = sum_s a[i][s] * v'[i][d][s] ----------
    #pragma unroll
    for (int r = 0; r < 4; ++r) {
        int i = ib + r;
        float pr[3] = {0.f, 0.f, 0.f};
        #pragma unroll
        for (int q = 0; q < 3; ++q) {
            int m4 = mb + 4 * q;
            int d = m4 >> 5, s4 = m4 & 31;
            float2 u0 = __bfloat1622float2(*(const bf162*)(s_a + i * 38 + s4));
            float2 u1 = __bfloat1622float2(*(const bf162*)(s_a + i * 38 + s4 + 2));
            pr[d] = fmaf(u0.x, va[r][4 * q + 0], pr[d]);
            pr[d] = fmaf(u0.y, va[r][4 * q + 1], pr[d]);
            pr[d] = fmaf(u1.x, va[r][4 * q + 2], pr[d]);
            pr[d] = fmaf(u1.y, va[r][4 * q + 3], pr[d]);
        }
        #pragma unroll
        for (int d = 0; d < 3; ++d) {
            float v = pr[d];
            v += __shfl_xor(v, 1);
            v += __shfl_xor(v, 2);
            v += __shfl_xor(v, 4);
            if ((t & 7) == 0) s_scr[i * 3 + d] = v;
        }
    }
    __syncthreads();

    // write out: out[b][i][d][n], note i*3+d == e
    for (int e = t; e < 384; e += 256)
        out[(b * 384 + e) * NN + n] = s_scr[e];
}

extern "C" void kernel_launch(void* const* d_in, const int* in_sizes, int n_in,
                              void* d_out, int out_size, void* d_ws, size_t ws_size,
                              hipStream_t stream) {
    const float* gxyz = (const float*)d_in[0];
    const float* gfts = (const float*)d_in[1];
    const float* qxyz = (const float*)d_in[2];
    const float* We1  = (const float*)d_in[3];
    const float* We2  = (const float*)d_in[4];
    const float* Wq   = (const float*)d_in[5];
    const float* Wk   = (const float*)d_in[6];
    const float* Wv   = (const float*)d_in[7];
    const float* Wr1  = (const float*)d_in[8];
    const float* Wr2  = (const float*)d_in[9];
    const float* Wstd = (const float*)d_in[10];
    const float* Wf1  = (const float*)d_in[11];
    const float* bf1  = (const float*)d_in[12];
    const float* Wf2  = (const float*)d_in[13];
    const float* bf2  = (const float*)d_in[14];
    float* out = (float*)d_out;
    float* ws  = (float*)d_ws;

    int use_t = (ws_size >= (size_t)WS_FULL_FLOATS * sizeof(float)) ? 1 : 0;

    (void)hipFuncSetAttribute((const void*)fused_main,
                              hipFuncAttributeMaxDynamicSharedMemorySize, SMEM_BYTES);

    prep1<<<32, 256, 0, stream>>>(We1, We2, ws);
    prep2<<<use_t ? 353 : 97, 256, 0, stream>>>(Wq, Wk, Wv, Wr1, Wr2, Wf1, Wf2, ws, use_t);
    fused_main<<<BB * NN, 256, SMEM_BYTES, stream>>>(gxyz, gfts, qxyz, Wstd,
                                                     Wf1, bf1, Wf2, bf2, ws, out, use_t);
}

// Round 5
// 528.780 us; speedup vs baseline: 3.3985x; 3.3985x over previous
//
#include <hip/hip_runtime.h>
#include <hip/hip_bf16.h>
#include <math.h>

typedef __hip_bfloat16  bf16;
typedef __hip_bfloat162 bf162;

#define BB   2
#define CINC 64
#define CAC  128
#define NN   1024
#define SSS  32

// ---- workspace layout (float offsets) ----
#define OFF_KT   0        // Wk2^T  [c(64)][i(128)]
#define OFF_VT   8192     // Wv2^T
#define OFF_QT   16384    // Wq2^T
#define OFF_WR   24576    // w_r [128]
#define OFF_WE21 24704    // We2@We1 [o(128)][c(64)]
#define WS_BASE_FLOATS 32896
#define OFF_F1T  32896    // Wf1^T [c(384)][o(128)]
#define OFF_F2T  82048    // Wf2^T [c(128)][o(128)]
#define WS_FULL_FLOATS 98432

// ---- shared memory layout (BYTE offsets) ----
// s_att bf16 [128][100] (96 used, stride 100 for bank spread).
// s_h / s_a (bf16 [128][38]) alias into s_att (dead after Phase E reads).
// s_scr holds z0 (f32 288, phases C/D) then red (f32 384, phase H).
#define S_ATT_B 0        // bf16[128][100] = 25600 B
#define S_H_B   0        // alias bf16[128][38] = 9728 B
#define S_A_B   9728     // alias bf16[128][38]
#define S_SCR_B 25600    // f32[384]
#define S_Q_B   27136    // f32[128*3]
#define S_XYZ_B 28672    // f32[96]
#define S_FT0_B 29056    // f32[192]
#define SMEM_BYTES 29824

// ---------- prep kernel 1: We21 = W_e2 @ W_e1 ----------
__global__ __launch_bounds__(256) void prep1(const float* __restrict__ We1,
                                             const float* __restrict__ We2,
                                             float* __restrict__ ws) {
    int e = blockIdx.x * 256 + threadIdx.x;   // 8192 entries, grid = 32
    int o = e >> 6, c = e & 63;
    float acc = 0.f;
    for (int m = 0; m < 128; ++m)
        acc = fmaf(We2[o * 128 + m], We1[m * 64 + c], acc);
    ws[OFF_WE21 + o * 64 + c] = acc;
}

// ---------- prep kernel 2: fused weights + transposes ----------
__global__ __launch_bounds__(256) void prep2(const float* __restrict__ Wq,
                                             const float* __restrict__ Wk,
                                             const float* __restrict__ Wv,
                                             const float* __restrict__ Wr1,
                                             const float* __restrict__ Wr2,
                                             const float* __restrict__ Wf1,
                                             const float* __restrict__ Wf2,
                                             float* __restrict__ ws, int use_t) {
    const float* we21 = ws + OFF_WE21;
    int e = blockIdx.x * 256 + threadIdx.x;
    if (e < 24576) {
        const float* W = (e < 8192) ? Wk : (e < 16384) ? Wv : Wq;
        float* dst = ws + ((e < 8192) ? OFF_KT : (e < 16384) ? OFF_VT : OFF_QT);
        int le = e & 8191;
        int i = le >> 6, c = le & 63;
        float acc = 0.f;
        for (int o = 0; o < 128; ++o)
            acc = fmaf(W[i * 128 + o], we21[o * 64 + c], acc);
        dst[c * 128 + i] = acc;
    } else if (e < 24704) {
        int i = e - 24576;
        float acc = 0.f;
        for (int m = 0; m < 64; ++m)
            acc = fmaf(Wr2[i * 64 + m], Wr1[m], acc);
        ws[OFF_WR + i] = acc;
    } else if (use_t) {
        if (e < 24704 + 49152) {
            int f = e - 24704;
            int c = f >> 7, o = f & 127;
            ws[OFF_F1T + f] = Wf1[o * 384 + c];
        } else if (e < 24704 + 49152 + 16384) {
            int f = e - (24704 + 49152);
            int c = f >> 7, o = f & 127;
            ws[OFF_F2T + c * 128 + o] = Wf2[o * 128 + c];
        }
    }
}

// ---------- main fused kernel: one block per (b, n) ----------
// __launch_bounds__(256,4): VGPR cap 128. (256,5) forced the allocator under
// the 64-VGPR wave-slot step -> ka/va spilled to scratch -> 7.8 GB HBM (R4).
__global__ __launch_bounds__(256, 4) void fused_main(
        const float* __restrict__ gxyz, const float* __restrict__ gfts,
        const float* __restrict__ qxyz, const float* __restrict__ Wstd,
        const float* __restrict__ Wf1,  const float* __restrict__ bf1,
        const float* __restrict__ Wf2,  const float* __restrict__ bf2,
        const float* __restrict__ ws,   float* __restrict__ out, int use_t) {
    extern __shared__ char smc[];
    bf16*  s_att = (bf16*)(smc + S_ATT_B);   // [128][100]
    bf16*  s_h   = (bf16*)(smc + S_H_B);     // alias [128][38]
    bf16*  s_a   = (bf16*)(smc + S_A_B);     // alias [128][38]
    float* s_scr = (float*)(smc + S_SCR_B);  // z0 (C/D) then red (H)
    float* s_q   = (float*)(smc + S_Q_B);
    float* s_xyz = (float*)(smc + S_XYZ_B);
    float* s_ft0 = (float*)(smc + S_FT0_B);

    const int t   = threadIdx.x;
    const int bid = blockIdx.x;
    const int b   = bid >> 10;
    const int n   = bid & 1023;

    const float* gb = gfts + (size_t)b * (CINC * 3 * NN * SSS) + n * SSS;

    // ---------- Phase A: stage fts s=0 columns + xyz_rel ----------
    if (t < 192) s_ft0[t] = gb[(size_t)t * (NN * SSS)];   // [c*3+d] at s=0
    if (t >= 160) {
        int id = t - 160;                // 0..95
        int d = id >> 5, s = id & 31;
        s_xyz[id] = gxyz[((b * NN + n) * SSS + s) * 3 + d] - qxyz[(b * NN + n) * 3 + d];
    }
    __syncthreads();

    // ---------- Phase A2: q[i][d] from s=0 columns ----------
    if (t < 128) {
        const float* qtw = ws + OFF_QT;
        float q0 = 0.f, q1 = 0.f, q2 = 0.f;
        for (int c = 0; c < 64; ++c) {
            float w = qtw[c * 128 + t];
            q0 = fmaf(w, s_ft0[c * 3 + 0], q0);
            q1 = fmaf(w, s_ft0[c * 3 + 1], q1);
            q2 = fmaf(w, s_ft0[c * 3 + 2], q2);
        }
        s_q[t * 3 + 0] = q0; s_q[t * 3 + 1] = q1; s_q[t * 3 + 2] = q2;
    }
    __syncthreads();

    // ---------- Phase B: k,v = Wk2/Wv2 @ fts, fts direct from global ----------
    const int ib = (t >> 3) << 2;    // 0..124
    const int mb = (t & 7) * 12;     // 0..84
    int offm[3];
    #pragma unroll
    for (int q = 0; q < 3; ++q) {
        int m4 = mb + 4 * q;
        offm[q] = (m4 >> 5) * (NN * SSS) + (m4 & 31);
    }
    float ka[4][12], va[4][12];
    #pragma unroll
    for (int r = 0; r < 4; ++r)
        #pragma unroll
        for (int j = 0; j < 12; ++j) { ka[r][j] = 0.f; va[r][j] = 0.f; }
    {
        const float* kt = ws + OFF_KT;
        const float* vt = ws + OFF_VT;
        #pragma unroll 2
        for (int c = 0; c < 64; ++c) {
            const float* fb = gb + c * (3 * NN * SSS);
            float4 f0 = *(const float4*)(fb + offm[0]);
            float4 f1 = *(const float4*)(fb + offm[1]);
            float4 f2 = *(const float4*)(fb + offm[2]);
            float4 wk = *(const float4*)(kt + c * 128 + ib);
            float4 wv = *(const float4*)(vt + c * 128 + ib);
            float f[12]  = {f0.x, f0.y, f0.z, f0.w, f1.x, f1.y, f1.z, f1.w,
                            f2.x, f2.y, f2.z, f2.w};
            float wks[4] = {wk.x, wk.y, wk.z, wk.w};
            float wvs[4] = {wv.x, wv.y, wv.z, wv.w};
            #pragma unroll
            for (int r = 0; r < 4; ++r)
                #pragma unroll
                for (int j = 0; j < 12; ++j) {
                    ka[r][j] = fmaf(wks[r], f[j], ka[r][j]);
                    va[r][j] = fmaf(wvs[r], f[j], va[r][j]);
                }
        }
    }
    // Phase B-post: attn = q - k + pos (-> bf16 LDS); v' = v + pos (registers)
    {
        float4 wr4 = *(const float4*)(ws + OFF_WR + ib);
        float wrs[4] = {wr4.x, wr4.y, wr4.z, wr4.w};
        #pragma unroll
        for (int r = 0; r < 4; ++r) {
            int i = ib + r;
            float qv[3] = {s_q[i * 3 + 0], s_q[i * 3 + 1], s_q[i * 3 + 2]};
            float av[12];
            #pragma unroll
            for (int j = 0; j < 12; ++j) {
                int m = mb + j;
                int d = m >> 5;
                float pos = wrs[r] * s_xyz[m];
                av[j] = qv[d] - ka[r][j] + pos;
                va[r][j] += pos;
            }
            bf16* ap = s_att + i * 100 + mb;     // mb even -> 4B aligned
            #pragma unroll
            for (int u = 0; u < 6; ++u)
                *(bf162*)(ap + 2 * u) =
                    __float22bfloat162_rn(make_float2(av[2 * u], av[2 * u + 1]));
        }
    }
    __syncthreads();

    // ---------- Phase C: z0[j][kk][s] = sum_i Wstd[j][i] * attn[i][kk][s] ----------
    if (t < 144) {
        int j  = t / 48;
        int rp = (t - j * 48) * 2;       // even rem in [0,96)
        const float* wrow = Wstd + j * 128;
        float acc0 = 0.f, acc1 = 0.f;
        for (int i = 0; i < 128; ++i) {
            float2 a2 = __bfloat1622float2(*(const bf162*)(s_att + i * 100 + rp));
            float w = wrow[i];
            acc0 = fmaf(w, a2.x, acc0);
            acc1 = fmaf(w, a2.y, acc1);
        }
        s_scr[j * 96 + rp]     = acc0;   // z0: layout j*96 + kk*32 + s
        s_scr[j * 96 + rp + 1] = acc1;
    }
    __syncthreads();

    // ---------- Phase D: attn2[i][kk][s] = sum_j attn[i][j][s]*z0[j][kk][s] ----------
    for (int e = t; e < 2048; e += 256) {
        int i  = e >> 4;
        int sp = (e & 15) * 2;           // even s
        float2 a0 = __bfloat1622float2(*(const bf162*)(s_att + i * 100 + sp));
        float2 a1 = __bfloat1622float2(*(const bf162*)(s_att + i * 100 + 32 + sp));
        float2 a2 = __bfloat1622float2(*(const bf162*)(s_att + i * 100 + 64 + sp));
        #pragma unroll
        for (int kk = 0; kk < 3; ++kk) {
            float zx0 = s_scr[0 * 96 + kk * 32 + sp], zx1 = s_scr[0 * 96 + kk * 32 + sp + 1];
            float zy0 = s_scr[1 * 96 + kk * 32 + sp], zy1 = s_scr[1 * 96 + kk * 32 + sp + 1];
            float zz0 = s_scr[2 * 96 + kk * 32 + sp], zz1 = s_scr[2 * 96 + kk * 32 + sp + 1];
            float x = a0.x * zx0 + a1.x * zy0 + a2.x * zz0;
            float y = a0.y * zx1 + a1.y * zy1 + a2.y * zz1;
            *(bf162*)(s_att + i * 100 + kk * 32 + sp) =
                __float22bfloat162_rn(make_float2(x, y));
        }
    }
    __syncthreads();

    // ---------- Phase E: h = relu(Wf1 @ attn2 + b_f1)  (4o x 4s tiles) ----------
    const int ob = (t >> 3) << 2;
    const int sb = (t & 7) << 2;
    {
        float hacc[4][4];
        #pragma unroll
        for (int r = 0; r < 4; ++r)
            #pragma unroll
            for (int x = 0; x < 4; ++x) hacc[r][x] = 0.f;
        if (use_t) {
            const float* f1t = ws + OFF_F1T;
            for (int i = 0; i < 128; ++i) {
                #pragma unroll
                for (int kk = 0; kk < 3; ++kk) {
                    float2 p0 = __bfloat1622float2(*(const bf162*)(s_att + i * 100 + kk * 32 + sb));
                    float2 p1 = __bfloat1622float2(*(const bf162*)(s_att + i * 100 + kk * 32 + sb + 2));
                    float4 w4 = *(const float4*)(f1t + (i * 3 + kk) * 128 + ob);
                    float av[4] = {p0.x, p0.y, p1.x, p1.y};
                    float w[4]  = {w4.x, w4.y, w4.z, w4.w};
                    #pragma unroll
                    for (int r = 0; r < 4; ++r)
                        #pragma unroll
                        for (int x = 0; x < 4; ++x)
                            hacc[r][x] = fmaf(w[r], av[x], hacc[r][x]);
                }
            }
        } else {
            for (int i = 0; i < 128; ++i) {
                #pragma unroll
                for (int kk = 0; kk < 3; ++kk) {
                    float2 p0 = __bfloat1622float2(*(const bf162*)(s_att + i * 100 + kk * 32 + sb));
                    float2 p1 = __bfloat1622float2(*(const bf162*)(s_att + i * 100 + kk * 32 + sb + 2));
                    float av[4] = {p0.x, p0.y, p1.x, p1.y};
                    int c = i * 3 + kk;
                    float w[4];
                    #pragma unroll
                    for (int r = 0; r < 4; ++r) w[r] = Wf1[(ob + r) * 384 + c];
                    #pragma unroll
                    for (int r = 0; r < 4; ++r)
                        #pragma unroll
                        for (int x = 0; x < 4; ++x)
                            hacc[r][x] = fmaf(w[r], av[x], hacc[r][x]);
                }
            }
        }
        // s_att fully consumed; barrier, then write h into the aliased region
        __syncthreads();
        #pragma unroll
        for (int r = 0; r < 4; ++r) {
            float bias = bf1[ob + r];
            float h0 = fmaxf(hacc[r][0] + bias, 0.f);
            float h1 = fmaxf(hacc[r][1] + bias, 0.f);
            float h2 = fmaxf(hacc[r][2] + bias, 0.f);
            float h3 = fmaxf(hacc[r][3] + bias, 0.f);
            bf16* hp = s_h + (ob + r) * 38 + sb;
            *(bf162*)(hp)     = __float22bfloat162_rn(make_float2(h0, h1));
            *(bf162*)(hp + 2) = __float22bfloat162_rn(make_float2(h2, h3));
        }
    }
    __syncthreads();

    // ---------- Phase F: logits a = Wf2 @ h + b_f2 ----------
    {
        float facc[4][4];
        #pragma unroll
        for (int r = 0; r < 4; ++r)
            #pragma unroll
            for (int x = 0; x < 4; ++x) facc[r][x] = 0.f;
        if (use_t) {
            const float* f2t = ws + OFF_F2T;
            for (int c = 0; c < 128; ++c) {
                float2 p0 = __bfloat1622float2(*(const bf162*)(s_h + c * 38 + sb));
                float2 p1 = __bfloat1622float2(*(const bf162*)(s_h + c * 38 + sb + 2));
                float4 w4 = *(const float4*)(f2t + c * 128 + ob);
                float hv[4] = {p0.x, p0.y, p1.x, p1.y};
                float w[4]  = {w4.x, w4.y, w4.z, w4.w};
                #pragma unroll
                for (int r = 0; r < 4; ++r)
                    #pragma unroll
                    for (int x = 0; x < 4; ++x)
                        facc[r][x] = fmaf(w[r], hv[x], facc[r][x]);
            }
        } else {
            for (int c = 0; c < 128; ++c) {
                float2 p0 = __bfloat1622float2(*(const bf162*)(s_h + c * 38 + sb));
                float2 p1 = __bfloat1622float2(*(const bf162*)(s_h + c * 38 + sb + 2));
                float hv[4] = {p0.x, p0.y, p1.x, p1.y};
                float w[4];
                #pragma unroll
                for (int r = 0; r < 4; ++r) w[r] = Wf2[(ob + r) * 128 + c];
                #pragma unroll
                for (int r = 0; r < 4; ++r)
                    #pragma unroll
                    for (int x = 0; x < 4; ++x)
                        facc[r][x] = fmaf(w[r], hv[x], facc[r][x]);
            }
        }
        #pragma unroll
        for (int r = 0; r < 4; ++r) {
            float bias = bf2[ob + r];
            bf16* ap = s_a + (ob + r) * 38 + sb;
            *(bf162*)(ap)     = __float22bfloat162_rn(
                                    make_float2(facc[r][0] + bias, facc[r][1] + bias));
            *(bf162*)(ap + 2) = __float22bfloat162_rn(
                                    make_float2(facc[r][2] + bias, facc[r][3] + bias));
        }
    }
    __syncthreads();

    // ---------- Phase G: softmax over s (scale 1/sqrt(128)) ----------
    if (t < 128) {
        bf16* row = s_a + t * 38;
        float vals[32];
        #pragma unroll
        for (int s2 = 0; s2 < 16; ++s2) {
            float2 p = __bfloat1622float2(*(const bf162*)(row + 2 * s2));
            vals[2 * s2] = p.x; vals[2 * s2 + 1] = p.y;
        }
        float mx = -INFINITY;
        #pragma unroll
        for (int s = 0; s < 32; ++s) mx = fmaxf(mx, vals[s]);
        const float inv = 0.08838834764831845f;   // 1/sqrt(128)
        float sum = 0.f;
        #pragma unroll
        for (int s = 0; s < 32; ++s) { vals[s] = __expf((vals[s] - mx) * inv); sum += vals[s]; }
        float rs = 1.f / sum;
        #pragma unroll
        for (int s2 = 0; s2 < 16; ++s2)
            *(bf162*)(row + 2 * s2) = __float22bfloat162_rn(
                make_float2(vals[2 * s2] * rs, vals[2 * s2 + 1] * rs));
    }
    __syncthreads();

    // ---------- Phase H: resi[i][d] = sum_s a[i][s] * v'[i][d][s] ----------
    #pragma unroll
    for (int r = 0; r < 4; ++r) {
        int i = ib + r;
        float pr[3] = {0.f, 0.f, 0.f};
        #pragma unroll
        for (int q = 0; q < 3; ++q) {
            int m4 = mb + 4 * q;
            int d = m4 >> 5, s4 = m4 & 31;
            float2 u0 = __bfloat1622float2(*(const bf162*)(s_a + i * 38 + s4));
            float2 u1 = __bfloat1622float2(*(const bf162*)(s_a + i * 38 + s4 + 2));
            pr[d] = fmaf(u0.x, va[r][4 * q + 0], pr[d]);
            pr[d] = fmaf(u0.y, va[r][4 * q + 1], pr[d]);
            pr[d] = fmaf(u1.x, va[r][4 * q + 2], pr[d]);
            pr[d] = fmaf(u1.y, va[r][4 * q + 3], pr[d]);
        }
        #pragma unroll
        for (int d = 0; d < 3; ++d) {
            float v = pr[d];
            v += __shfl_xor(v, 1);
            v += __shfl_xor(v, 2);
            v += __shfl_xor(v, 4);
            if ((t & 7) == 0) s_scr[i * 3 + d] = v;
        }
    }
    __syncthreads();

    // write out: out[b][i][d][n], note i*3+d == e
    for (int e = t; e < 384; e += 256)
        out[(b * 384 + e) * NN + n] = s_scr[e];
}

extern "C" void kernel_launch(void* const* d_in, const int* in_sizes, int n_in,
                              void* d_out, int out_size, void* d_ws, size_t ws_size,
                              hipStream_t stream) {
    const float* gxyz = (const float*)d_in[0];
    const float* gfts = (const float*)d_in[1];
    const float* qxyz = (const float*)d_in[2];
    const float* We1  = (const float*)d_in[3];
    const float* We2  = (const float*)d_in[4];
    const float* Wq   = (const float*)d_in[5];
    const float* Wk   = (const float*)d_in[6];
    const float* Wv   = (const float*)d_in[7];
    const float* Wr1  = (const float*)d_in[8];
    const float* Wr2  = (const float*)d_in[9];
    const float* Wstd = (const float*)d_in[10];
    const float* Wf1  = (const float*)d_in[11];
    const float* bf1  = (const float*)d_in[12];
    const float* Wf2  = (const float*)d_in[13];
    const float* bf2  = (const float*)d_in[14];
    float* out = (float*)d_out;
    float* ws  = (float*)d_ws;

    int use_t = (ws_size >= (size_t)WS_FULL_FLOATS * sizeof(float)) ? 1 : 0;

    (void)hipFuncSetAttribute((const void*)fused_main,
                              hipFuncAttributeMaxDynamicSharedMemorySize, SMEM_BYTES);

    prep1<<<32, 256, 0, stream>>>(We1, We2, ws);
    prep2<<<use_t ? 353 : 97, 256, 0, stream>>>(Wq, Wk, Wv, Wr1, Wr2, Wf1, Wf2, ws, use_t);
    fused_main<<<BB * NN, 256, SMEM_BYTES, stream>>>(gxyz, gfts, qxyz, Wstd,
                                                     Wf1, bf1, Wf2, bf2, ws, out, use_t);
}

// Round 6
// 401.683 us; speedup vs baseline: 4.4738x; 1.3164x over previous
//
#include <hip/hip_runtime.h>
#include <hip/hip_bf16.h>
#include <math.h>

typedef __hip_bfloat16  bf16;
typedef __hip_bfloat162 bf162;

#define BB   2
#define CINC 64
#define CAC  128
#define NN   1024
#define SSS  32

// ---- workspace layout (float offsets) ----
#define OFF_KT   0        // Wk2^T  [c(64)][i(128)]
#define OFF_VT   8192     // Wv2^T
#define OFF_QT   16384    // Wq2^T
#define OFF_WR   24576    // w_r [128]
#define OFF_WE21 24704    // We2@We1 [o(128)][c(64)]
#define WS_BASE_FLOATS 32896
#define OFF_F1T  32896    // Wf1^T [c(384)][o(128)]
#define OFF_F2T  82048    // Wf2^T [c(128)][o(128)]
#define WS_FULL_FLOATS 98432

// ---- shared memory layout (BYTE offsets) ----
// s_att bf16 [128][100] (96 used, stride 100 for bank spread).
// s_h / s_a (bf16 [128][38]) alias into s_att (dead after Phase E reads).
// s_scr holds z0 (f32 288, phases C/D) then red (f32 384, phase H).
#define S_ATT_B 0        // bf16[128][100] = 25600 B
#define S_H_B   0        // alias bf16[128][38] = 9728 B
#define S_A_B   9728     // alias bf16[128][38]
#define S_SCR_B 25600    // f32[384]
#define S_Q_B   27136    // f32[128*3]
#define S_XYZ_B 28672    // f32[96]
#define S_FT0_B 29056    // f32[192]
#define SMEM_BYTES 29824

// ---------- prep kernel 1: We21 = W_e2 @ W_e1 ----------
__global__ __launch_bounds__(256) void prep1(const float* __restrict__ We1,
                                             const float* __restrict__ We2,
                                             float* __restrict__ ws) {
    int e = blockIdx.x * 256 + threadIdx.x;   // 8192 entries, grid = 32
    int o = e >> 6, c = e & 63;
    float acc = 0.f;
    for (int m = 0; m < 128; ++m)
        acc = fmaf(We2[o * 128 + m], We1[m * 64 + c], acc);
    ws[OFF_WE21 + o * 64 + c] = acc;
}

// ---------- prep kernel 2: fused weights + transposes ----------
__global__ __launch_bounds__(256) void prep2(const float* __restrict__ Wq,
                                             const float* __restrict__ Wk,
                                             const float* __restrict__ Wv,
                                             const float* __restrict__ Wr1,
                                             const float* __restrict__ Wr2,
                                             const float* __restrict__ Wf1,
                                             const float* __restrict__ Wf2,
                                             float* __restrict__ ws, int use_t) {
    const float* we21 = ws + OFF_WE21;
    int e = blockIdx.x * 256 + threadIdx.x;
    if (e < 24576) {
        const float* W = (e < 8192) ? Wk : (e < 16384) ? Wv : Wq;
        float* dst = ws + ((e < 8192) ? OFF_KT : (e < 16384) ? OFF_VT : OFF_QT);
        int le = e & 8191;
        int i = le >> 6, c = le & 63;
        float acc = 0.f;
        for (int o = 0; o < 128; ++o)
            acc = fmaf(W[i * 128 + o], we21[o * 64 + c], acc);
        dst[c * 128 + i] = acc;
    } else if (e < 24704) {
        int i = e - 24576;
        float acc = 0.f;
        for (int m = 0; m < 64; ++m)
            acc = fmaf(Wr2[i * 64 + m], Wr1[m], acc);
        ws[OFF_WR + i] = acc;
    } else if (use_t) {
        if (e < 24704 + 49152) {
            int f = e - 24704;
            int c = f >> 7, o = f & 127;
            ws[OFF_F1T + f] = Wf1[o * 384 + c];
        } else if (e < 24704 + 49152 + 16384) {
            int f = e - (24704 + 49152);
            int c = f >> 7, o = f & 127;
            ws[OFF_F2T + c * 128 + o] = Wf2[o * 128 + c];
        }
    }
}

// ---------- main fused kernel: one block per (b, n) ----------
// __launch_bounds__(256,3): this compiler budgets VGPR ~ 256/min_waves_per_EU
// (R3: 3->84, R5: 4->64, R4: 5->48). Our ka/va working set (96 f32) fits at 84
// but spills at 64/48 (R4: 7.8 GB, R5: 0.2 GB HBM scratch traffic). HW wave
// slots step at VGPR={64,128,256}, so 84 VGPR still yields 4 waves/SIMD.
__global__ __launch_bounds__(256, 3) void fused_main(
        const float* __restrict__ gxyz, const float* __restrict__ gfts,
        const float* __restrict__ qxyz, const float* __restrict__ Wstd,
        const float* __restrict__ Wf1,  const float* __restrict__ bf1,
        const float* __restrict__ Wf2,  const float* __restrict__ bf2,
        const float* __restrict__ ws,   float* __restrict__ out, int use_t) {
    extern __shared__ char smc[];
    bf16*  s_att = (bf16*)(smc + S_ATT_B);   // [128][100]
    bf16*  s_h   = (bf16*)(smc + S_H_B);     // alias [128][38]
    bf16*  s_a   = (bf16*)(smc + S_A_B);     // alias [128][38]
    float* s_scr = (float*)(smc + S_SCR_B);  // z0 (C/D) then red (H)
    float* s_q   = (float*)(smc + S_Q_B);
    float* s_xyz = (float*)(smc + S_XYZ_B);
    float* s_ft0 = (float*)(smc + S_FT0_B);

    const int t   = threadIdx.x;
    const int bid = blockIdx.x;
    const int b   = bid >> 10;
    const int n   = bid & 1023;

    const float* gb = gfts + (size_t)b * (CINC * 3 * NN * SSS) + n * SSS;

    // ---------- Phase A: stage fts s=0 columns + xyz_rel ----------
    if (t < 192) s_ft0[t] = gb[(size_t)t * (NN * SSS)];   // [c*3+d] at s=0
    if (t >= 160) {
        int id = t - 160;                // 0..95
        int d = id >> 5, s = id & 31;
        s_xyz[id] = gxyz[((b * NN + n) * SSS + s) * 3 + d] - qxyz[(b * NN + n) * 3 + d];
    }
    __syncthreads();

    // ---------- Phase A2: q[i][d] from s=0 columns ----------
    if (t < 128) {
        const float* qtw = ws + OFF_QT;
        float q0 = 0.f, q1 = 0.f, q2 = 0.f;
        for (int c = 0; c < 64; ++c) {
            float w = qtw[c * 128 + t];
            q0 = fmaf(w, s_ft0[c * 3 + 0], q0);
            q1 = fmaf(w, s_ft0[c * 3 + 1], q1);
            q2 = fmaf(w, s_ft0[c * 3 + 2], q2);
        }
        s_q[t * 3 + 0] = q0; s_q[t * 3 + 1] = q1; s_q[t * 3 + 2] = q2;
    }
    __syncthreads();

    // ---------- Phase B: k,v = Wk2/Wv2 @ fts, fts direct from global ----------
    const int ib = (t >> 3) << 2;    // 0..124
    const int mb = (t & 7) * 12;     // 0..84
    int offm[3];
    #pragma unroll
    for (int q = 0; q < 3; ++q) {
        int m4 = mb + 4 * q;
        offm[q] = (m4 >> 5) * (NN * SSS) + (m4 & 31);
    }
    float ka[4][12], va[4][12];
    #pragma unroll
    for (int r = 0; r < 4; ++r)
        #pragma unroll
        for (int j = 0; j < 12; ++j) { ka[r][j] = 0.f; va[r][j] = 0.f; }
    {
        const float* kt = ws + OFF_KT;
        const float* vt = ws + OFF_VT;
        #pragma unroll 2
        for (int c = 0; c < 64; ++c) {
            const float* fb = gb + c * (3 * NN * SSS);
            float4 f0 = *(const float4*)(fb + offm[0]);
            float4 f1 = *(const float4*)(fb + offm[1]);
            float4 f2 = *(const float4*)(fb + offm[2]);
            float4 wk = *(const float4*)(kt + c * 128 + ib);
            float4 wv = *(const float4*)(vt + c * 128 + ib);
            float f[12]  = {f0.x, f0.y, f0.z, f0.w, f1.x, f1.y, f1.z, f1.w,
                            f2.x, f2.y, f2.z, f2.w};
            float wks[4] = {wk.x, wk.y, wk.z, wk.w};
            float wvs[4] = {wv.x, wv.y, wv.z, wv.w};
            #pragma unroll
            for (int r = 0; r < 4; ++r)
                #pragma unroll
                for (int j = 0; j < 12; ++j) {
                    ka[r][j] = fmaf(wks[r], f[j], ka[r][j]);
                    va[r][j] = fmaf(wvs[r], f[j], va[r][j]);
                }
        }
    }
    // Phase B-post: attn = q - k + pos (-> bf16 LDS); v' = v + pos (registers)
    {
        float4 wr4 = *(const float4*)(ws + OFF_WR + ib);
        float wrs[4] = {wr4.x, wr4.y, wr4.z, wr4.w};
        #pragma unroll
        for (int r = 0; r < 4; ++r) {
            int i = ib + r;
            float qv[3] = {s_q[i * 3 + 0], s_q[i * 3 + 1], s_q[i * 3 + 2]};
            float av[12];
            #pragma unroll
            for (int j = 0; j < 12; ++j) {
                int m = mb + j;
                int d = m >> 5;
                float pos = wrs[r] * s_xyz[m];
                av[j] = qv[d] - ka[r][j] + pos;
                va[r][j] += pos;
            }
            bf16* ap = s_att + i * 100 + mb;     // mb even -> 4B aligned
            #pragma unroll
            for (int u = 0; u < 6; ++u)
                *(bf162*)(ap + 2 * u) =
                    __float22bfloat162_rn(make_float2(av[2 * u], av[2 * u + 1]));
        }
    }
    __syncthreads();

    // ---------- Phase C: z0[j][kk][s] = sum_i Wstd[j][i] * attn[i][kk][s] ----------
    if (t < 144) {
        int j  = t / 48;
        int rp = (t - j * 48) * 2;       // even rem in [0,96)
        const float* wrow = Wstd + j * 128;
        float acc0 = 0.f, acc1 = 0.f;
        for (int i = 0; i < 128; ++i) {
            float2 a2 = __bfloat1622float2(*(const bf162*)(s_att + i * 100 + rp));
            float w = wrow[i];
            acc0 = fmaf(w, a2.x, acc0);
            acc1 = fmaf(w, a2.y, acc1);
        }
        s_scr[j * 96 + rp]     = acc0;   // z0: layout j*96 + kk*32 + s
        s_scr[j * 96 + rp + 1] = acc1;
    }
    __syncthreads();

    // ---------- Phase D: attn2[i][kk][s] = sum_j attn[i][j][s]*z0[j][kk][s] ----------
    for (int e = t; e < 2048; e += 256) {
        int i  = e >> 4;
        int sp = (e & 15) * 2;           // even s
        float2 a0 = __bfloat1622float2(*(const bf162*)(s_att + i * 100 + sp));
        float2 a1 = __bfloat1622float2(*(const bf162*)(s_att + i * 100 + 32 + sp));
        float2 a2 = __bfloat1622float2(*(const bf162*)(s_att + i * 100 + 64 + sp));
        #pragma unroll
        for (int kk = 0; kk < 3; ++kk) {
            float zx0 = s_scr[0 * 96 + kk * 32 + sp], zx1 = s_scr[0 * 96 + kk * 32 + sp + 1];
            float zy0 = s_scr[1 * 96 + kk * 32 + sp], zy1 = s_scr[1 * 96 + kk * 32 + sp + 1];
            float zz0 = s_scr[2 * 96 + kk * 32 + sp], zz1 = s_scr[2 * 96 + kk * 32 + sp + 1];
            float x = a0.x * zx0 + a1.x * zy0 + a2.x * zz0;
            float y = a0.y * zx1 + a1.y * zy1 + a2.y * zz1;
            *(bf162*)(s_att + i * 100 + kk * 32 + sp) =
                __float22bfloat162_rn(make_float2(x, y));
        }
    }
    __syncthreads();

    // ---------- Phase E: h = relu(Wf1 @ attn2 + b_f1)  (4o x 4s tiles) ----------
    const int ob = (t >> 3) << 2;
    const int sb = (t & 7) << 2;
    {
        float hacc[4][4];
        #pragma unroll
        for (int r = 0; r < 4; ++r)
            #pragma unroll
            for (int x = 0; x < 4; ++x) hacc[r][x] = 0.f;
        if (use_t) {
            const float* f1t = ws + OFF_F1T;
            for (int i = 0; i < 128; ++i) {
                #pragma unroll
                for (int kk = 0; kk < 3; ++kk) {
                    float2 p0 = __bfloat1622float2(*(const bf162*)(s_att + i * 100 + kk * 32 + sb));
                    float2 p1 = __bfloat1622float2(*(const bf162*)(s_att + i * 100 + kk * 32 + sb + 2));
                    float4 w4 = *(const float4*)(f1t + (i * 3 + kk) * 128 + ob);
                    float av[4] = {p0.x, p0.y, p1.x, p1.y};
                    float w[4]  = {w4.x, w4.y, w4.z, w4.w};
                    #pragma unroll
                    for (int r = 0; r < 4; ++r)
                        #pragma unroll
                        for (int x = 0; x < 4; ++x)
                            hacc[r][x] = fmaf(w[r], av[x], hacc[r][x]);
                }
            }
        } else {
            for (int i = 0; i < 128; ++i) {
                #pragma unroll
                for (int kk = 0; kk < 3; ++kk) {
                    float2 p0 = __bfloat1622float2(*(const bf162*)(s_att + i * 100 + kk * 32 + sb));
                    float2 p1 = __bfloat1622float2(*(const bf162*)(s_att + i * 100 + kk * 32 + sb + 2));
                    float av[4] = {p0.x, p0.y, p1.x, p1.y};
                    int c = i * 3 + kk;
                    float w[4];
                    #pragma unroll
                    for (int r = 0; r < 4; ++r) w[r] = Wf1[(ob + r) * 384 + c];
                    #pragma unroll
                    for (int r = 0; r < 4; ++r)
                        #pragma unroll
                        for (int x = 0; x < 4; ++x)
                            hacc[r][x] = fmaf(w[r], av[x], hacc[r][x]);
                }
            }
        }
        // s_att fully consumed; barrier, then write h into the aliased region
        __syncthreads();
        #pragma unroll
        for (int r = 0; r < 4; ++r) {
            float bias = bf1[ob + r];
            float h0 = fmaxf(hacc[r][0] + bias, 0.f);
            float h1 = fmaxf(hacc[r][1] + bias, 0.f);
            float h2 = fmaxf(hacc[r][2] + bias, 0.f);
            float h3 = fmaxf(hacc[r][3] + bias, 0.f);
            bf16* hp = s_h + (ob + r) * 38 + sb;
            *(bf162*)(hp)     = __float22bfloat162_rn(make_float2(h0, h1));
            *(bf162*)(hp + 2) = __float22bfloat162_rn(make_float2(h2, h3));
        }
    }
    __syncthreads();

    // ---------- Phase F: logits a = Wf2 @ h + b_f2 ----------
    {
        float facc[4][4];
        #pragma unroll
        for (int r = 0; r < 4; ++r)
            #pragma unroll
            for (int x = 0; x < 4; ++x) facc[r][x] = 0.f;
        if (use_t) {
            const float* f2t = ws + OFF_F2T;
            for (int c = 0; c < 128; ++c) {
                float2 p0 = __bfloat1622float2(*(const bf162*)(s_h + c * 38 + sb));
                float2 p1 = __bfloat1622float2(*(const bf162*)(s_h + c * 38 + sb + 2));
                float4 w4 = *(const float4*)(f2t + c * 128 + ob);
                float hv[4] = {p0.x, p0.y, p1.x, p1.y};
                float w[4]  = {w4.x, w4.y, w4.z, w4.w};
                #pragma unroll
                for (int r = 0; r < 4; ++r)
                    #pragma unroll
                    for (int x = 0; x < 4; ++x)
                        facc[r][x] = fmaf(w[r], hv[x], facc[r][x]);
            }
        } else {
            for (int c = 0; c < 128; ++c) {
                float2 p0 = __bfloat1622float2(*(const bf162*)(s_h + c * 38 + sb));
                float2 p1 = __bfloat1622float2(*(const bf162*)(s_h + c * 38 + sb + 2));
                float hv[4] = {p0.x, p0.y, p1.x, p1.y};
                float w[4];
                #pragma unroll
                for (int r = 0; r < 4; ++r) w[r] = Wf2[(ob + r) * 128 + c];
                #pragma unroll
                for (int r = 0; r < 4; ++r)
                    #pragma unroll
                    for (int x = 0; x < 4; ++x)
                        facc[r][x] = fmaf(w[r], hv[x], facc[r][x]);
            }
        }
        #pragma unroll
        for (int r = 0; r < 4; ++r) {
            float bias = bf2[ob + r];
            bf16* ap = s_a + (ob + r) * 38 + sb;
            *(bf162*)(ap)     = __float22bfloat162_rn(
                                    make_float2(facc[r][0] + bias, facc[r][1] + bias));
            *(bf162*)(ap + 2) = __float22bfloat162_rn(
                                    make_float2(facc[r][2] + bias, facc[r][3] + bias));
        }
    }
    __syncthreads();

    // ---------- Phase G: softmax over s (scale 1/sqrt(128)) ----------
    if (t < 128) {
        bf16* row = s_a + t * 38;
        float vals[32];
        #pragma unroll
        for (int s2 = 0; s2 < 16; ++s2) {
            float2 p = __bfloat1622float2(*(const bf162*)(row + 2 * s2));
            vals[2 * s2] = p.x; vals[2 * s2 + 1] = p.y;
        }
        float mx = -INFINITY;
        #pragma unroll
        for (int s = 0; s < 32; ++s) mx = fmaxf(mx, vals[s]);
        const float inv = 0.08838834764831845f;   // 1/sqrt(128)
        float sum = 0.f;
        #pragma unroll
        for (int s = 0; s < 32; ++s) { vals[s] = __expf((vals[s] - mx) * inv); sum += vals[s]; }
        float rs = 1.f / sum;
        #pragma unroll
        for (int s2 = 0; s2 < 16; ++s2)
            *(bf162*)(row + 2 * s2) = __float22bfloat162_rn(
                make_float2(vals[2 * s2] * rs, vals[2 * s2 + 1] * rs));
    }
    __syncthreads();

    // ---------- Phase H: resi[i][d] = sum_s a[i][s] * v'[i][d][s] ----------
    #pragma unroll
    for (int r = 0; r < 4; ++r) {
        int i = ib + r;
        float pr[3] = {0.f, 0.f, 0.f};
        #pragma unroll
        for (int q = 0; q < 3; ++q) {
            int m4 = mb + 4 * q;
            int d = m4 >> 5, s4 = m4 & 31;
            float2 u0 = __bfloat1622float2(*(const bf162*)(s_a + i * 38 + s4));
            float2 u1 = __bfloat1622float2(*(const bf162*)(s_a + i * 38 + s4 + 2));
            pr[d] = fmaf(u0.x, va[r][4 * q + 0], pr[d]);
            pr[d] = fmaf(u0.y, va[r][4 * q + 1], pr[d]);
            pr[d] = fmaf(u1.x, va[r][4 * q + 2], pr[d]);
            pr[d] = fmaf(u1.y, va[r][4 * q + 3], pr[d]);
        }
        #pragma unroll
        for (int d = 0; d < 3; ++d) {
            float v = pr[d];
            v += __shfl_xor(v, 1);
            v += __shfl_xor(v, 2);
            v += __shfl_xor(v, 4);
            if ((t & 7) == 0) s_scr[i * 3 + d] = v;
        }
    }
    __syncthreads();

    // write out: out[b][i][d][n], note i*3+d == e
    for (int e = t; e < 384; e += 256)
        out[(b * 384 + e) * NN + n] = s_scr[e];
}

extern "C" void kernel_launch(void* const* d_in, const int* in_sizes, int n_in,
                              void* d_out, int out_size, void* d_ws, size_t ws_size,
                              hipStream_t stream) {
    const float* gxyz = (const float*)d_in[0];
    const float* gfts = (const float*)d_in[1];
    const float* qxyz = (const float*)d_in[2];
    const float* We1  = (const float*)d_in[3];
    const float* We2  = (const float*)d_in[4];
    const float* Wq   = (const float*)d_in[5];
    const float* Wk   = (const float*)d_in[6];
    const float* Wv   = (const float*)d_in[7];
    const float* Wr1  = (const float*)d_in[8];
    const float* Wr2  = (const float*)d_in[9];
    const float* Wstd = (const float*)d_in[10];
    const float* Wf1  = (const float*)d_in[11];
    const float* bf1  = (const float*)d_in[12];
    const float* Wf2  = (const float*)d_in[13];
    const float* bf2  = (const float*)d_in[14];
    float* out = (float*)d_out;
    float* ws  = (float*)d_ws;

    int use_t = (ws_size >= (size_t)WS_FULL_FLOATS * sizeof(float)) ? 1 : 0;

    (void)hipFuncSetAttribute((const void*)fused_main,
                              hipFuncAttributeMaxDynamicSharedMemorySize, SMEM_BYTES);

    prep1<<<32, 256, 0, stream>>>(We1, We2, ws);
    prep2<<<use_t ? 353 : 97, 256, 0, stream>>>(Wq, Wk, Wv, Wr1, Wr2, Wf1, Wf2, ws, use_t);
    fused_main<<<BB * NN, 256, SMEM_BYTES, stream>>>(gxyz, gfts, qxyz, Wstd,
                                                     Wf1, bf1, Wf2, bf2, ws, out, use_t);
}

// Round 7
// 291.136 us; speedup vs baseline: 6.1726x; 1.3797x over previous
//
#include <hip/hip_runtime.h>
#include <hip/hip_bf16.h>
#include <math.h>

typedef __hip_bfloat16  bf16;
typedef __hip_bfloat162 bf162;
typedef __attribute__((ext_vector_type(8))) short short8;   // 8 bf16 = 4 VGPRs (MFMA A/B frag)
typedef __attribute__((ext_vector_type(4))) short s16x4;
typedef __attribute__((ext_vector_type(4))) float f32x4;    // MFMA C/D frag

#define BB   2
#define CINC 64
#define CAC  128
#define NN   1024
#define SSS  32

// ---- workspace layout (float offsets) ----
#define OFF_KT   0        // Wk2^T  f32 [c(64)][i(128)]   (Phase B, VALU)
#define OFF_VT   8192     // Wv2^T
#define OFF_QT   16384    // Wq2^T
#define OFF_WR   24576    // w_r [128]
#define OFF_WE21 24704    // We2@We1 [o(128)][c(64)]      (ends 32896)
#define OFF_F1B  32896    // bf16[o=128][kappa=384], kappa=kk*128+i  (24576 f32 slots)
#define OFF_F2B  57472    // bf16[o=128][c=128]                      (8192 f32 slots)
#define WS_NEED_FLOATS 65664

// ---- shared memory layout (BYTE offsets) ----
// att_t bf16[j=3][s=32][i stride 136] : stride 136 bf16 = 272 B (16B-aligned,
// bank offset 4) -> b128 fragment reads are i-contiguous.
// h_t (bf16[32][136]) and a_t (bf16[32][136]) alias into att_t (dead after E).
#define S_ATT_B 0         // 3*32*136*2 = 26112 B ; h_t at +0, a_t at +8704
#define S_SCR_B 26112     // f32[384]: z0 (C/D) then red (H)
#define S_Q_B   27648     // f32[128*3]
#define S_XYZ_B 29184     // f32[96]
#define S_FT0_B 29568     // f32[192]
#define SMEM_BYTES 30336

__device__ __forceinline__ float bf2f(short s) {
    unsigned int u = ((unsigned int)(unsigned short)s) << 16;
    return __uint_as_float(u);
}
__device__ __forceinline__ short f2bf(float f) {
    bf16 h = __float2bfloat16(f);
    return *reinterpret_cast<short*>(&h);
}
__device__ __forceinline__ unsigned pk2(float a, float b) {
    bf162 p = __float22bfloat162_rn(make_float2(a, b));
    return *reinterpret_cast<unsigned*>(&p);
}

// ---------- prep kernel 1: We21 = W_e2 @ W_e1 ----------
__global__ __launch_bounds__(256) void prep1(const float* __restrict__ We1,
                                             const float* __restrict__ We2,
                                             float* __restrict__ ws) {
    int e = blockIdx.x * 256 + threadIdx.x;   // 8192 entries, grid = 32
    int o = e >> 6, c = e & 63;
    float acc = 0.f;
    for (int m = 0; m < 128; ++m)
        acc = fmaf(We2[o * 128 + m], We1[m * 64 + c], acc);
    ws[OFF_WE21 + o * 64 + c] = acc;
}

// ---------- prep kernel 2: fused weights + bf16 fragment-ordered FFN weights ----------
__global__ __launch_bounds__(256) void prep2(const float* __restrict__ Wq,
                                             const float* __restrict__ Wk,
                                             const float* __restrict__ Wv,
                                             const float* __restrict__ Wr1,
                                             const float* __restrict__ Wr2,
                                             const float* __restrict__ Wf1,
                                             const float* __restrict__ Wf2,
                                             float* __restrict__ ws, int use_t) {
    const float* we21 = ws + OFF_WE21;
    int e = blockIdx.x * 256 + threadIdx.x;
    if (e < 24576) {
        const float* W = (e < 8192) ? Wk : (e < 16384) ? Wv : Wq;
        float* dst = ws + ((e < 8192) ? OFF_KT : (e < 16384) ? OFF_VT : OFF_QT);
        int le = e & 8191;
        int i = le >> 6, c = le & 63;
        float acc = 0.f;
        for (int o = 0; o < 128; ++o)
            acc = fmaf(W[i * 128 + o], we21[o * 64 + c], acc);
        dst[c * 128 + i] = acc;
    } else if (e < 24704) {
        int i = e - 24576;
        float acc = 0.f;
        for (int m = 0; m < 64; ++m)
            acc = fmaf(Wr2[i * 64 + m], Wr1[m], acc);
        ws[OFF_WR + i] = acc;
    } else if (use_t) {
        if (e < 24704 + 49152) {
            int f = e - 24704;                 // F1B[o][kappa], kappa = kk*128+i
            int o = f / 384, kp = f - o * 384;
            int c = (kp & 127) * 3 + (kp >> 7);
            ((bf16*)(ws + OFF_F1B))[f] = __float2bfloat16(Wf1[o * 384 + c]);
        } else if (e < 24704 + 49152 + 16384) {
            int f = e - (24704 + 49152);       // F2B[o][c] = Wf2 (same layout)
            ((bf16*)(ws + OFF_F2B))[f] = __float2bfloat16(Wf2[f]);
        }
    }
}

// ---------- main fused kernel: one block per (b, n) ----------
// (256,2): VGPR cap 128 (compiler budget ~256/min_waves). Peak live set ~110
// (48 va + MFMA accs in AGPRs). HW wave slots: vgpr<=128 -> 4 waves/SIMD.
__global__ __launch_bounds__(256, 2) void fused_main(
        const float* __restrict__ gxyz, const float* __restrict__ gfts,
        const float* __restrict__ qxyz, const float* __restrict__ Wstd,
        const float* __restrict__ Wf1,  const float* __restrict__ bf1,
        const float* __restrict__ Wf2,  const float* __restrict__ bf2,
        const float* __restrict__ ws,   float* __restrict__ out, int use_t) {
    extern __shared__ char smc[];
    short* s_att = (short*)(smc + S_ATT_B);   // att_t[j][s][136]
    short* h_t   = s_att;                     // alias [32][136] (valid post-E)
    short* a_t   = s_att + 4352;              // alias [32][136]
    float* s_scr = (float*)(smc + S_SCR_B);
    float* s_q   = (float*)(smc + S_Q_B);
    float* s_xyz = (float*)(smc + S_XYZ_B);
    float* s_ft0 = (float*)(smc + S_FT0_B);

    const int t    = threadIdx.x;
    const int bid  = blockIdx.x;
    const int b    = bid >> 10;
    const int n    = bid & 1023;
    const int w    = t >> 6;        // wave id 0..3
    const int lane = t & 63;
    const int quad = lane >> 4;
    const int lq   = lane & 15;

    const float* gb = gfts + (size_t)b * (CINC * 3 * NN * SSS) + n * SSS;

    // ---------- Phase A: stage fts s=0 columns + xyz_rel ----------
    if (t < 192) s_ft0[t] = gb[(size_t)t * (NN * SSS)];   // [c*3+d] at s=0
    if (t >= 160) {
        int id = t - 160;                // 0..95
        int d = id >> 5, s = id & 31;
        s_xyz[id] = gxyz[((b * NN + n) * SSS + s) * 3 + d] - qxyz[(b * NN + n) * 3 + d];
    }
    __syncthreads();

    // ---------- Phase A2: q[i][d] from s=0 columns ----------
    if (t < 128) {
        const float* qtw = ws + OFF_QT;
        float q0 = 0.f, q1 = 0.f, q2 = 0.f;
        for (int c = 0; c < 64; ++c) {
            float wq = qtw[c * 128 + t];
            q0 = fmaf(wq, s_ft0[c * 3 + 0], q0);
            q1 = fmaf(wq, s_ft0[c * 3 + 1], q1);
            q2 = fmaf(wq, s_ft0[c * 3 + 2], q2);
        }
        s_q[t * 3 + 0] = q0; s_q[t * 3 + 1] = q1; s_q[t * 3 + 2] = q2;
    }
    __syncthreads();

    // ---------- Phase B (VALU): k,v = Wk2/Wv2 @ fts, fts direct from global ----------
    const int ib = (t >> 3) << 2;    // 0..124
    const int mb = (t & 7) * 12;     // 0..84
    int offm[3];
    #pragma unroll
    for (int q = 0; q < 3; ++q) {
        int m4 = mb + 4 * q;
        offm[q] = (m4 >> 5) * (NN * SSS) + (m4 & 31);
    }
    float ka[4][12], va[4][12];
    #pragma unroll
    for (int r = 0; r < 4; ++r)
        #pragma unroll
        for (int j = 0; j < 12; ++j) { ka[r][j] = 0.f; va[r][j] = 0.f; }
    {
        const float* kt = ws + OFF_KT;
        const float* vt = ws + OFF_VT;
        #pragma unroll 2
        for (int c = 0; c < 64; ++c) {
            const float* fb = gb + c * (3 * NN * SSS);
            float4 f0 = *(const float4*)(fb + offm[0]);
            float4 f1 = *(const float4*)(fb + offm[1]);
            float4 f2 = *(const float4*)(fb + offm[2]);
            float4 wk = *(const float4*)(kt + c * 128 + ib);
            float4 wv = *(const float4*)(vt + c * 128 + ib);
            float f[12]  = {f0.x, f0.y, f0.z, f0.w, f1.x, f1.y, f1.z, f1.w,
                            f2.x, f2.y, f2.z, f2.w};
            float wks[4] = {wk.x, wk.y, wk.z, wk.w};
            float wvs[4] = {wv.x, wv.y, wv.z, wv.w};
            #pragma unroll
            for (int r = 0; r < 4; ++r)
                #pragma unroll
                for (int j = 0; j < 12; ++j) {
                    ka[r][j] = fmaf(wks[r], f[j], ka[r][j]);
                    va[r][j] = fmaf(wvs[r], f[j], va[r][j]);
                }
        }
    }
    // Phase B-post: attn = q - k + pos (in place into ka); v' = v + pos (regs).
    // Write att_t[m][ib..ib+3]: 12 x b64 i-contiguous stores.
    {
        float4 wr4 = *(const float4*)(ws + OFF_WR + ib);
        float wrs[4] = {wr4.x, wr4.y, wr4.z, wr4.w};
        #pragma unroll
        for (int r = 0; r < 4; ++r) {
            int i = ib + r;
            float qv[3] = {s_q[i * 3 + 0], s_q[i * 3 + 1], s_q[i * 3 + 2]};
            #pragma unroll
            for (int j = 0; j < 12; ++j) {
                int m = mb + j;
                int d = m >> 5;
                float pos = wrs[r] * s_xyz[m];
                ka[r][j] = qv[d] - ka[r][j] + pos;
                va[r][j] += pos;
            }
        }
        #pragma unroll
        for (int j = 0; j < 12; ++j) {
            int m = mb + j;                    // row = d*32+s = m
            uint2 pk;
            pk.x = pk2(ka[0][j], ka[1][j]);
            pk.y = pk2(ka[2][j], ka[3][j]);
            *(uint2*)(s_att + m * 136 + ib) = pk;
        }
    }
    __syncthreads();

    // ---------- Phase C: z0[j][kk][s] = sum_i Wstd[j][i] * attn[i][kk][s] ----------
    for (int o = t; o < 288; o += 256) {
        int j = o / 96;
        int rem = o - j * 96;                  // kk*32+s
        const float* wrow = Wstd + j * 128;
        const short* ap = s_att + rem * 136;   // att_t[kk][s][.]
        float acc = 0.f;
        #pragma unroll 4
        for (int i8 = 0; i8 < 16; ++i8) {
            short8 v8 = *(const short8*)(ap + i8 * 8);
            #pragma unroll
            for (int u = 0; u < 8; ++u)
                acc = fmaf(wrow[i8 * 8 + u], bf2f(v8[u]), acc);
        }
        s_scr[o] = acc;                        // z0: j*96 + kk*32 + s
    }
    __syncthreads();

    // ---------- Phase D: attn2[i][kk][s] = sum_j attn[i][j][s]*z0[j][kk][s] (in place) ----------
    for (int u = t; u < 512; u += 256) {
        int s  = u >> 4;
        int i0 = (u & 15) * 8;
        float z[3][3];
        #pragma unroll
        for (int j = 0; j < 3; ++j)
            #pragma unroll
            for (int kk = 0; kk < 3; ++kk)
                z[j][kk] = s_scr[j * 96 + kk * 32 + s];
        float af[3][8];
        #pragma unroll
        for (int j = 0; j < 3; ++j) {
            short8 v8 = *(const short8*)(s_att + (j * 32 + s) * 136 + i0);
            #pragma unroll
            for (int x = 0; x < 8; ++x) af[j][x] = bf2f(v8[x]);
        }
        #pragma unroll
        for (int kk = 0; kk < 3; ++kk) {
            short8 o8;
            #pragma unroll
            for (int x = 0; x < 8; ++x)
                o8[x] = f2bf(af[0][x] * z[0][kk] + af[1][x] * z[1][kk] + af[2][x] * z[2][kk]);
            *(short8*)(s_att + (kk * 32 + s) * 136 + i0) = o8;
        }
    }
    __syncthreads();

    // ---------- Phase E: h = relu(Wf1 @ attn2 + b_f1) via MFMA 16x16x32 bf16 ----------
    // GEMM M=128(o) N=32(s) K=384(kappa=kk*128+i). Wave w: o-rows 32w..32w+31.
    const int o0 = 32 * w;
    f32x4 eacc[2][2];
    {
        f32x4 zz = {0.f, 0.f, 0.f, 0.f};
        eacc[0][0] = zz; eacc[0][1] = zz; eacc[1][0] = zz; eacc[1][1] = zz;
    }
    if (use_t) {
        const short* f1b = (const short*)(ws + OFF_F1B);
        const short* ab0 = f1b + (o0 + lq) * 384 + quad * 8;        // A[m=lq][k=quad*8+j]
        const short* ab1 = ab0 + 16 * 384;
        #pragma unroll 2
        for (int ks = 0; ks < 12; ++ks) {
            int kk = ks >> 2;
            int i0 = (ks & 3) * 32 + quad * 8;
            short8 a0 = *(const short8*)(ab0 + ks * 32);
            short8 a1 = *(const short8*)(ab1 + ks * 32);
            const short* bp = s_att + (kk * 32) * 136 + i0;          // B[k][n=s]
            short8 b0 = *(const short8*)(bp + lq * 136);
            short8 b1 = *(const short8*)(bp + (lq + 16) * 136);
            eacc[0][0] = __builtin_amdgcn_mfma_f32_16x16x32_bf16(a0, b0, eacc[0][0], 0, 0, 0);
            eacc[0][1] = __builtin_amdgcn_mfma_f32_16x16x32_bf16(a0, b1, eacc[0][1], 0, 0, 0);
            eacc[1][0] = __builtin_amdgcn_mfma_f32_16x16x32_bf16(a1, b0, eacc[1][0], 0, 0, 0);
            eacc[1][1] = __builtin_amdgcn_mfma_f32_16x16x32_bf16(a1, b1, eacc[1][1], 0, 0, 0);
        }
    } else {
        // fallback (ws too small): direct f32 weights, correctness-only
        int o = t >> 1, sh = (t & 1) * 16;
        float hv[16];
        #pragma unroll
        for (int x = 0; x < 16; ++x) hv[x] = 0.f;
        for (int i = 0; i < 128; ++i)
            for (int kk = 0; kk < 3; ++kk) {
                float wv = Wf1[o * 384 + i * 3 + kk];
                const short* ap = s_att + (kk * 32 + sh) * 136 + i;
                #pragma unroll
                for (int x = 0; x < 16; ++x)
                    hv[x] = fmaf(wv, bf2f(ap[x * 136]), hv[x]);
            }
        #pragma unroll
        for (int x = 0; x < 16; ++x) eacc[x >> 3][(x >> 2) & 1][x & 3] = hv[x];  // stash
    }
    __syncthreads();     // all att_t reads complete before h_t overwrites it

    // E epilogue: h_t[s][o] (bf16), relu+bias
    if (use_t) {
        #pragma unroll
        for (int mt = 0; mt < 2; ++mt) {
            int ob = o0 + mt * 16 + quad * 4;
            float4 bb = *(const float4*)(bf1 + ob);
            float bv[4] = {bb.x, bb.y, bb.z, bb.w};
            #pragma unroll
            for (int nt = 0; nt < 2; ++nt) {
                f32x4 c = eacc[mt][nt];
                int s = nt * 16 + lq;
                uint2 pk;
                pk.x = pk2(fmaxf(c[0] + bv[0], 0.f), fmaxf(c[1] + bv[1], 0.f));
                pk.y = pk2(fmaxf(c[2] + bv[2], 0.f), fmaxf(c[3] + bv[3], 0.f));
                *(uint2*)(h_t + s * 136 + ob) = pk;
            }
        }
    } else {
        int o = t >> 1, sh = (t & 1) * 16;
        float bias = bf1[o];
        #pragma unroll
        for (int x = 0; x < 16; ++x)
            h_t[(sh + x) * 136 + o] = f2bf(fmaxf(eacc[x >> 3][(x >> 2) & 1][x & 3] + bias, 0.f));
    }
    __syncthreads();

    // ---------- Phase F: logits a = Wf2 @ h + b_f2 via MFMA (M=128,N=32,K=128) ----------
    if (use_t) {
        f32x4 facc[2][2];
        {
            f32x4 zz = {0.f, 0.f, 0.f, 0.f};
            facc[0][0] = zz; facc[0][1] = zz; facc[1][0] = zz; facc[1][1] = zz;
        }
        const short* f2b = (const short*)(ws + OFF_F2B);
        const short* ab0 = f2b + (o0 + lq) * 128 + quad * 8;
        const short* ab1 = ab0 + 16 * 128;
        #pragma unroll 2
        for (int ks = 0; ks < 4; ++ks) {
            int c0 = ks * 32 + quad * 8;
            short8 a0 = *(const short8*)(ab0 + ks * 32);
            short8 a1 = *(const short8*)(ab1 + ks * 32);
            short8 b0 = *(const short8*)(h_t + lq * 136 + c0);
            short8 b1 = *(const short8*)(h_t + (lq + 16) * 136 + c0);
            facc[0][0] = __builtin_amdgcn_mfma_f32_16x16x32_bf16(a0, b0, facc[0][0], 0, 0, 0);
            facc[0][1] = __builtin_amdgcn_mfma_f32_16x16x32_bf16(a0, b1, facc[0][1], 0, 0, 0);
            facc[1][0] = __builtin_amdgcn_mfma_f32_16x16x32_bf16(a1, b0, facc[1][0], 0, 0, 0);
            facc[1][1] = __builtin_amdgcn_mfma_f32_16x16x32_bf16(a1, b1, facc[1][1], 0, 0, 0);
        }
        // epilogue: a_t[s][o] (region disjoint from h_t; att_t dead) — no barrier needed
        #pragma unroll
        for (int mt = 0; mt < 2; ++mt) {
            int ob = o0 + mt * 16 + quad * 4;
            float4 bb = *(const float4*)(bf2 + ob);
            float bv[4] = {bb.x, bb.y, bb.z, bb.w};
            #pragma unroll
            for (int nt = 0; nt < 2; ++nt) {
                f32x4 c = facc[mt][nt];
                int s = nt * 16 + lq;
                uint2 pk;
                pk.x = pk2(c[0] + bv[0], c[1] + bv[1]);
                pk.y = pk2(c[2] + bv[2], c[3] + bv[3]);
                *(uint2*)(a_t + s * 136 + ob) = pk;
            }
        }
    } else {
        int o = t >> 1, sh = (t & 1) * 16;
        float av[16];
        #pragma unroll
        for (int x = 0; x < 16; ++x) av[x] = 0.f;
        for (int c = 0; c < 128; ++c) {
            float wv = Wf2[o * 128 + c];
            #pragma unroll
            for (int x = 0; x < 16; ++x)
                av[x] = fmaf(wv, bf2f(h_t[(sh + x) * 136 + c]), av[x]);
        }
        float bias = bf2[o];
        #pragma unroll
        for (int x = 0; x < 16; ++x)
            a_t[(sh + x) * 136 + o] = f2bf(av[x] + bias);
    }
    __syncthreads();

    // ---------- Phase G: softmax over s (scale 1/sqrt(128)), a_t[s][i] ----------
    if (t < 128) {
        float vals[32];
        #pragma unroll
        for (int s = 0; s < 32; ++s) vals[s] = bf2f(a_t[s * 136 + t]);
        float mx = -INFINITY;
        #pragma unroll
        for (int s = 0; s < 32; ++s) mx = fmaxf(mx, vals[s]);
        const float inv = 0.08838834764831845f;   // 1/sqrt(128)
        float sum = 0.f;
        #pragma unroll
        for (int s = 0; s < 32; ++s) { vals[s] = __expf((vals[s] - mx) * inv); sum += vals[s]; }
        float rs = 1.f / sum;
        #pragma unroll
        for (int s = 0; s < 32; ++s) a_t[s * 136 + t] = f2bf(vals[s] * rs);
    }
    __syncthreads();

    // ---------- Phase H: resi[i][d] = sum_s a[i][s] * v'[i][d][s] ----------
    {
        float pr[4][3];
        #pragma unroll
        for (int r = 0; r < 4; ++r)
            #pragma unroll
            for (int d = 0; d < 3; ++d) pr[r][d] = 0.f;
        #pragma unroll
        for (int j = 0; j < 12; ++j) {
            int m = mb + j;
            int s = m & 31, d = m >> 5;
            s16x4 a4 = *(const s16x4*)(a_t + s * 136 + ib);
            #pragma unroll
            for (int r = 0; r < 4; ++r)
                pr[r][d] = fmaf(bf2f(a4[r]), va[r][j], pr[r][d]);
        }
        #pragma unroll
        for (int r = 0; r < 4; ++r) {
            int i = ib + r;
            #pragma unroll
            for (int d = 0; d < 3; ++d) {
                float v = pr[r][d];
                v += __shfl_xor(v, 1);
                v += __shfl_xor(v, 2);
                v += __shfl_xor(v, 4);
                if ((t & 7) == 0) s_scr[i * 3 + d] = v;
            }
        }
    }
    __syncthreads();

    // write out: out[b][i][d][n], note i*3+d == e
    for (int e = t; e < 384; e += 256)
        out[(b * 384 + e) * NN + n] = s_scr[e];
}

extern "C" void kernel_launch(void* const* d_in, const int* in_sizes, int n_in,
                              void* d_out, int out_size, void* d_ws, size_t ws_size,
                              hipStream_t stream) {
    const float* gxyz = (const float*)d_in[0];
    const float* gfts = (const float*)d_in[1];
    const float* qxyz = (const float*)d_in[2];
    const float* We1  = (const float*)d_in[3];
    const float* We2  = (const float*)d_in[4];
    const float* Wq   = (const float*)d_in[5];
    const float* Wk   = (const float*)d_in[6];
    const float* Wv   = (const float*)d_in[7];
    const float* Wr1  = (const float*)d_in[8];
    const float* Wr2  = (const float*)d_in[9];
    const float* Wstd = (const float*)d_in[10];
    const float* Wf1  = (const float*)d_in[11];
    const float* bf1  = (const float*)d_in[12];
    const float* Wf2  = (const float*)d_in[13];
    const float* bf2  = (const float*)d_in[14];
    float* out = (float*)d_out;
    float* ws  = (float*)d_ws;

    int use_t = (ws_size >= (size_t)WS_NEED_FLOATS * sizeof(float)) ? 1 : 0;

    (void)hipFuncSetAttribute((const void*)fused_main,
                              hipFuncAttributeMaxDynamicSharedMemorySize, SMEM_BYTES);

    prep1<<<32, 256, 0, stream>>>(We1, We2, ws);
    prep2<<<use_t ? 353 : 97, 256, 0, stream>>>(Wq, Wk, Wv, Wr1, Wr2, Wf1, Wf2, ws, use_t);
    fused_main<<<BB * NN, 256, SMEM_BYTES, stream>>>(gxyz, gfts, qxyz, Wstd,
                                                     Wf1, bf1, Wf2, bf2, ws, out, use_t);
}

// Round 8
// 190.550 us; speedup vs baseline: 9.4309x; 1.5279x over previous
//
#include <hip/hip_runtime.h>
#include <hip/hip_bf16.h>
#include <math.h>

typedef __hip_bfloat16  bf16;
typedef __hip_bfloat162 bf162;
typedef __attribute__((ext_vector_type(8))) short short8;   // 8 bf16 (MFMA A/B frag)
typedef __attribute__((ext_vector_type(4))) float f32x4;    // MFMA C/D frag

#define BB   2
#define CINC 64
#define NN   1024
#define SSS  32
#define NS   (NN * SSS)

// ---- workspace layout (float offsets) ----
// ws_size proven >= 262656 B (R7 ran the MFMA path); we need 229888 B.
#define OFF_QT   0        // f32 [c=64][i=128]  (Phase A2)
#define OFF_WR   8192     // f32 [128]
#define OFF_WE21 8320     // f32 [o=128][c=64]
#define OFF_KB   16512    // bf16 [i=128][c=64] = 4096 f32 slots (Phase B B-frags)
#define OFF_VB   20608    // bf16 [i=128][c=64]
#define OFF_F1B  24704    // bf16 [o=128][kappa=384], kappa=kk*128+i
#define OFF_F2B  49280    // bf16 [o=128][c=128]
#define WS_NEED_FLOATS 57472

// ---- shared memory (BYTE offsets) ----
// att_t bf16[j*32+s][stride 136] (h_t at +0, a_t at +8704 alias in, post-E).
// fts_b bf16[m=96][stride 72] — 72 = mult of 8 shorts => 16B-aligned rows.
// s_scr f32[384]: wr (A/B) -> z0 (C/D) -> red (H); disjoint lifetimes.
#define S_ATT_B 0         // 26112 B
#define S_FTS_B 26112     // 96*72*2 = 13824 B
#define S_SCR_B 39936     // f32[384]
#define S_Q_B   41472     // f32[128*3]
#define S_XYZ_B 43008     // f32[96]
#define SMEM_BYTES 43392  // -> 3 blocks/CU by LDS

__device__ __forceinline__ float bf2f(short s) {
    unsigned int u = ((unsigned int)(unsigned short)s) << 16;
    return __uint_as_float(u);
}
__device__ __forceinline__ short f2bf(float f) {
    bf16 h = __float2bfloat16(f);
    return *reinterpret_cast<short*>(&h);
}
__device__ __forceinline__ unsigned pk2(float a, float b) {
    bf162 p = __float22bfloat162_rn(make_float2(a, b));
    return *reinterpret_cast<unsigned*>(&p);
}

// ---------- prep kernel 1: We21 = W_e2 @ W_e1 ----------
__global__ __launch_bounds__(256) void prep1(const float* __restrict__ We1,
                                             const float* __restrict__ We2,
                                             float* __restrict__ ws) {
    int e = blockIdx.x * 256 + threadIdx.x;   // 8192 entries, grid = 32
    int o = e >> 6, c = e & 63;
    float acc = 0.f;
    for (int m = 0; m < 128; ++m)
        acc = fmaf(We2[o * 128 + m], We1[m * 64 + c], acc);
    ws[OFF_WE21 + o * 64 + c] = acc;
}

// ---------- prep kernel 2: fused weights (QT f32; KB/VB bf16; F1B/F2B bf16) ----------
__global__ __launch_bounds__(256) void prep2(const float* __restrict__ Wq,
                                             const float* __restrict__ Wk,
                                             const float* __restrict__ Wv,
                                             const float* __restrict__ Wr1,
                                             const float* __restrict__ Wr2,
                                             const float* __restrict__ Wf1,
                                             const float* __restrict__ Wf2,
                                             float* __restrict__ ws) {
    const float* we21 = ws + OFF_WE21;
    int e = blockIdx.x * 256 + threadIdx.x;
    if (e < 8192) {                            // QT f32 [c][i]
        int i = e >> 6, c = e & 63;
        float acc = 0.f;
        for (int o = 0; o < 128; ++o)
            acc = fmaf(Wq[i * 128 + o], we21[o * 64 + c], acc);
        ws[OFF_QT + c * 128 + i] = acc;
    } else if (e < 24576) {                    // KB / VB bf16 [i][c]
        int le = e - 8192;
        const float* W = (le < 8192) ? Wk : Wv;
        bf16* dst = (bf16*)(ws + ((le < 8192) ? OFF_KB : OFF_VB));
        int li = le & 8191;
        int i = li >> 6, c = li & 63;
        float acc = 0.f;
        for (int o = 0; o < 128; ++o)
            acc = fmaf(W[i * 128 + o], we21[o * 64 + c], acc);
        dst[i * 64 + c] = __float2bfloat16(acc);
    } else if (e < 24704) {                    // w_r f32
        int i = e - 24576;
        float acc = 0.f;
        for (int m = 0; m < 64; ++m)
            acc = fmaf(Wr2[i * 64 + m], Wr1[m], acc);
        ws[OFF_WR + i] = acc;
    } else if (e < 24704 + 49152) {            // F1B[o][kappa], kappa = kk*128+i
        int f = e - 24704;
        int o = f / 384, kp = f - o * 384;
        int c = (kp & 127) * 3 + (kp >> 7);
        ((bf16*)(ws + OFF_F1B))[f] = __float2bfloat16(Wf1[o * 384 + c]);
    } else if (e < 24704 + 49152 + 16384) {    // F2B[o][c]
        int f = e - (24704 + 49152);
        ((bf16*)(ws + OFF_F2B))[f] = __float2bfloat16(Wf2[f]);
    }
}

// ---------- main fused kernel: one block per (b, n) ----------
// (256,2): VGPR cap 128 (compiler budget ~256/min_waves — R3/R4/R5 series).
// Peak live ~115 (va 48 in C-layout + B-frags 32 + A/temps).
__global__ __launch_bounds__(256, 2) void fused_main(
        const float* __restrict__ gxyz, const float* __restrict__ gfts,
        const float* __restrict__ qxyz, const float* __restrict__ Wstd,
        const float* __restrict__ bf1,  const float* __restrict__ bf2,
        const float* __restrict__ ws,   float* __restrict__ out) {
    extern __shared__ char smc[];
    short* s_att = (short*)(smc + S_ATT_B);   // att_t[(kk*32+s)][136]
    short* h_t   = s_att;                     // alias [32][136] (post-E)
    short* a_t   = s_att + 4352;              // alias [32][136]
    short* fts_s = (short*)(smc + S_FTS_B);   // fts_b[m][72]
    float* s_scr = (float*)(smc + S_SCR_B);   // wr -> z0 -> red
    float* s_q   = (float*)(smc + S_Q_B);
    float* s_xyz = (float*)(smc + S_XYZ_B);

    const int t    = threadIdx.x;
    const int bid  = blockIdx.x;
    const int b    = bid >> 10;
    const int n    = bid & 1023;
    const int w    = t >> 6;        // wave id 0..3
    const int lane = t & 63;
    const int quad = lane >> 4;
    const int lq   = lane & 15;
    const int wb   = 32 * w;        // wave's i-base (B,H) / o-base (E,F)

    const float* gb = gfts + (size_t)b * (CINC * 3 * NS) + n * SSS;

    // ---------- Phase A: stage fts_b (bf16, transposed) + xyz_rel + wr ----------
    for (int l4 = t; l4 < 1536; l4 += 256) {       // 6 iters, coalesced float4
        int c  = l4 / 24;
        int m4 = (l4 - c * 24) * 4;                // 0,4,...,92
        int d  = m4 >> 5, s = m4 & 31;
        float4 f = *(const float4*)(gb + (c * 3 + d) * NS + s);
        fts_s[(m4 + 0) * 72 + c] = f2bf(f.x);
        fts_s[(m4 + 1) * 72 + c] = f2bf(f.y);
        fts_s[(m4 + 2) * 72 + c] = f2bf(f.z);
        fts_s[(m4 + 3) * 72 + c] = f2bf(f.w);
    }
    if (t >= 160) {
        int id = t - 160;                // 0..95
        int d = id >> 5, s = id & 31;
        s_xyz[id] = gxyz[((b * NN + n) * SSS + s) * 3 + d] - qxyz[(b * NN + n) * 3 + d];
    }
    if (t < 128) s_scr[t] = ws[OFF_WR + t];        // wr (consumed in B, before C)
    __syncthreads();

    // ---------- Phase A2: q[i][d] from fts_b rows m=0/32/64 (broadcast reads) ----------
    if (t < 128) {
        const float* qtw = ws + OFF_QT;
        float q0 = 0.f, q1 = 0.f, q2 = 0.f;
        for (int c = 0; c < 64; ++c) {
            float wq = qtw[c * 128 + t];
            q0 = fmaf(wq, bf2f(fts_s[c]),           q0);
            q1 = fmaf(wq, bf2f(fts_s[32 * 72 + c]), q1);
            q2 = fmaf(wq, bf2f(fts_s[64 * 72 + c]), q2);
        }
        s_q[t * 3 + 0] = q0; s_q[t * 3 + 1] = q1; s_q[t * 3 + 2] = q2;
    }
    __syncthreads();

    // ---------- Phase B (MFMA): k,v GEMMs  D[m][i] = fts[m][c]·W[i][c] ----------
    // M=96(m) N=128(i, split 32/wave) K=64(c). D layout: col=lq->i, row=quad*4+reg->m.
    f32x4 va[6][2];   // v' = v + pos, C-layout, persists to Phase H
    {
        const short* kb = (const short*)(ws + OFF_KB);
        const short* vb = (const short*)(ws + OFF_VB);
        short8 Bk[2][2], Bv[2][2];
        #pragma unroll
        for (int it = 0; it < 2; ++it) {
            int irow = (wb + it * 16 + lq) * 64 + quad * 8;
            Bk[it][0] = *(const short8*)(kb + irow);
            Bk[it][1] = *(const short8*)(kb + irow + 32);
            Bv[it][0] = *(const short8*)(vb + irow);
            Bv[it][1] = *(const short8*)(vb + irow + 32);
        }
        #pragma unroll
        for (int mt = 0; mt < 6; ++mt) {
            const short* ap = fts_s + (mt * 16 + lq) * 72 + quad * 8;
            short8 A0 = *(const short8*)(ap);
            short8 A1 = *(const short8*)(ap + 32);
            int d = mt >> 1;
            #pragma unroll
            for (int it = 0; it < 2; ++it) {
                f32x4 kk = {0.f, 0.f, 0.f, 0.f};
                kk = __builtin_amdgcn_mfma_f32_16x16x32_bf16(A0, Bk[it][0], kk, 0, 0, 0);
                kk = __builtin_amdgcn_mfma_f32_16x16x32_bf16(A1, Bk[it][1], kk, 0, 0, 0);
                f32x4 vv = {0.f, 0.f, 0.f, 0.f};
                vv = __builtin_amdgcn_mfma_f32_16x16x32_bf16(A0, Bv[it][0], vv, 0, 0, 0);
                vv = __builtin_amdgcn_mfma_f32_16x16x32_bf16(A1, Bv[it][1], vv, 0, 0, 0);
                int i = wb + it * 16 + lq;
                float qd  = s_q[i * 3 + d];
                float wri = s_scr[i];
                #pragma unroll
                for (int reg = 0; reg < 4; ++reg) {
                    int m = mt * 16 + quad * 4 + reg;      // m = d*32+s
                    float pos = wri * s_xyz[m];
                    s_att[m * 136 + i] = f2bf(qd - kk[reg] + pos);  // att_t disjoint from fts_b
                    va[mt][it][reg] = vv[reg] + pos;
                }
            }
        }
    }
    __syncthreads();

    // ---------- Phase C: z0[j][kk][s] = sum_i Wstd[j][i] * attn[i][kk][s] ----------
    for (int o = t; o < 288; o += 256) {
        int j = o / 96;
        int rem = o - j * 96;                  // kk*32+s
        const float* wrow = Wstd + j * 128;
        const short* ap = s_att + rem * 136;
        float acc = 0.f;
        #pragma unroll 4
        for (int i8 = 0; i8 < 16; ++i8) {
            short8 v8 = *(const short8*)(ap + i8 * 8);
            #pragma unroll
            for (int u = 0; u < 8; ++u)
                acc = fmaf(wrow[i8 * 8 + u], bf2f(v8[u]), acc);
        }
        s_scr[o] = acc;                        // z0: j*96 + kk*32 + s
    }
    __syncthreads();

    // ---------- Phase D: attn2[i][kk][s] = sum_j attn[i][j][s]*z0[j][kk][s] (in place) ----------
    for (int u = t; u < 512; u += 256) {
        int s  = u >> 4;
        int i0 = (u & 15) * 8;
        float z[3][3];
        #pragma unroll
        for (int j = 0; j < 3; ++j)
            #pragma unroll
            for (int kk = 0; kk < 3; ++kk)
                z[j][kk] = s_scr[j * 96 + kk * 32 + s];
        float af[3][8];
        #pragma unroll
        for (int j = 0; j < 3; ++j) {
            short8 v8 = *(const short8*)(s_att + (j * 32 + s) * 136 + i0);
            #pragma unroll
            for (int x = 0; x < 8; ++x) af[j][x] = bf2f(v8[x]);
        }
        #pragma unroll
        for (int kk = 0; kk < 3; ++kk) {
            short8 o8;
            #pragma unroll
            for (int x = 0; x < 8; ++x)
                o8[x] = f2bf(af[0][x] * z[0][kk] + af[1][x] * z[1][kk] + af[2][x] * z[2][kk]);
            *(short8*)(s_att + (kk * 32 + s) * 136 + i0) = o8;
        }
    }
    __syncthreads();

    // ---------- Phase E: h = relu(Wf1 @ attn2 + b_f1) via MFMA (M=128,N=32,K=384) ----------
    f32x4 eacc[2][2];
    {
        f32x4 zz = {0.f, 0.f, 0.f, 0.f};
        eacc[0][0] = zz; eacc[0][1] = zz; eacc[1][0] = zz; eacc[1][1] = zz;
        const short* f1b = (const short*)(ws + OFF_F1B);
        const short* ab0 = f1b + (wb + lq) * 384 + quad * 8;
        const short* ab1 = ab0 + 16 * 384;
        #pragma unroll 2
        for (int ks = 0; ks < 12; ++ks) {
            int kk = ks >> 2;
            int ic = (ks & 3) * 32 + quad * 8;
            short8 a0 = *(const short8*)(ab0 + ks * 32);
            short8 a1 = *(const short8*)(ab1 + ks * 32);
            const short* bp = s_att + (kk * 32) * 136 + ic;
            short8 b0 = *(const short8*)(bp + lq * 136);
            short8 b1 = *(const short8*)(bp + (lq + 16) * 136);
            eacc[0][0] = __builtin_amdgcn_mfma_f32_16x16x32_bf16(a0, b0, eacc[0][0], 0, 0, 0);
            eacc[0][1] = __builtin_amdgcn_mfma_f32_16x16x32_bf16(a0, b1, eacc[0][1], 0, 0, 0);
            eacc[1][0] = __builtin_amdgcn_mfma_f32_16x16x32_bf16(a1, b0, eacc[1][0], 0, 0, 0);
            eacc[1][1] = __builtin_amdgcn_mfma_f32_16x16x32_bf16(a1, b1, eacc[1][1], 0, 0, 0);
        }
    }
    __syncthreads();     // all att_t reads complete before h_t overwrites it

    // E epilogue: h_t[s][o] (bf16), relu+bias
    #pragma unroll
    for (int mt = 0; mt < 2; ++mt) {
        int ob = wb + mt * 16 + quad * 4;
        float4 bb = *(const float4*)(bf1 + ob);
        float bv[4] = {bb.x, bb.y, bb.z, bb.w};
        #pragma unroll
        for (int nt = 0; nt < 2; ++nt) {
            f32x4 c = eacc[mt][nt];
            int s = nt * 16 + lq;
            uint2 pk;
            pk.x = pk2(fmaxf(c[0] + bv[0], 0.f), fmaxf(c[1] + bv[1], 0.f));
            pk.y = pk2(fmaxf(c[2] + bv[2], 0.f), fmaxf(c[3] + bv[3], 0.f));
            *(uint2*)(h_t + s * 136 + ob) = pk;
        }
    }
    __syncthreads();

    // ---------- Phase F: logits = Wf2 @ h + b_f2 via MFMA (M=128,N=32,K=128) ----------
    {
        f32x4 facc[2][2];
        f32x4 zz = {0.f, 0.f, 0.f, 0.f};
        facc[0][0] = zz; facc[0][1] = zz; facc[1][0] = zz; facc[1][1] = zz;
        const short* f2b = (const short*)(ws + OFF_F2B);
        const short* ab0 = f2b + (wb + lq) * 128 + quad * 8;
        const short* ab1 = ab0 + 16 * 128;
        #pragma unroll 2
        for (int ks = 0; ks < 4; ++ks) {
            int c0 = ks * 32 + quad * 8;
            short8 a0 = *(const short8*)(ab0 + ks * 32);
            short8 a1 = *(const short8*)(ab1 + ks * 32);
            short8 b0 = *(const short8*)(h_t + lq * 136 + c0);
            short8 b1 = *(const short8*)(h_t + (lq + 16) * 136 + c0);
            facc[0][0] = __builtin_amdgcn_mfma_f32_16x16x32_bf16(a0, b0, facc[0][0], 0, 0, 0);
            facc[0][1] = __builtin_amdgcn_mfma_f32_16x16x32_bf16(a0, b1, facc[0][1], 0, 0, 0);
            facc[1][0] = __builtin_amdgcn_mfma_f32_16x16x32_bf16(a1, b0, facc[1][0], 0, 0, 0);
            facc[1][1] = __builtin_amdgcn_mfma_f32_16x16x32_bf16(a1, b1, facc[1][1], 0, 0, 0);
        }
        // a_t region disjoint from h_t; att_t dead -> no barrier before stores
        #pragma unroll
        for (int mt = 0; mt < 2; ++mt) {
            int ob = wb + mt * 16 + quad * 4;
            float4 bb = *(const float4*)(bf2 + ob);
            float bv[4] = {bb.x, bb.y, bb.z, bb.w};
            #pragma unroll
            for (int nt = 0; nt < 2; ++nt) {
                f32x4 c = facc[mt][nt];
                int s = nt * 16 + lq;
                uint2 pk;
                pk.x = pk2(c[0] + bv[0], c[1] + bv[1]);
                pk.y = pk2(c[2] + bv[2], c[3] + bv[3]);
                *(uint2*)(a_t + s * 136 + ob) = pk;
            }
        }
    }
    __syncthreads();

    // ---------- Phase G: softmax over s (scale 1/sqrt(128)), a_t[s][i] ----------
    if (t < 128) {
        float vals[32];
        #pragma unroll
        for (int s = 0; s < 32; ++s) vals[s] = bf2f(a_t[s * 136 + t]);
        float mx = -INFINITY;
        #pragma unroll
        for (int s = 0; s < 32; ++s) mx = fmaxf(mx, vals[s]);
        const float inv = 0.08838834764831845f;   // 1/sqrt(128)
        float sum = 0.f;
        #pragma unroll
        for (int s = 0; s < 32; ++s) { vals[s] = __expf((vals[s] - mx) * inv); sum += vals[s]; }
        float rs = 1.f / sum;
        #pragma unroll
        for (int s = 0; s < 32; ++s) a_t[s * 136 + t] = f2bf(vals[s] * rs);
    }
    __syncthreads();

    // ---------- Phase H: resi[i][d] = sum_s a[s][i] * v'[i][m=d*32+s] ----------
    // va C-layout: m = mt*16+quad*4+reg, i = wb+it*16+lq. Reduce over quads.
    {
        float pr[2][3];
        #pragma unroll
        for (int it = 0; it < 2; ++it)
            #pragma unroll
            for (int d = 0; d < 3; ++d) pr[it][d] = 0.f;
        #pragma unroll
        for (int mt = 0; mt < 6; ++mt) {
            int d = mt >> 1;
            #pragma unroll
            for (int it = 0; it < 2; ++it) {
                int i = wb + it * 16 + lq;
                #pragma unroll
                for (int reg = 0; reg < 4; ++reg) {
                    int s = (mt & 1) * 16 + quad * 4 + reg;
                    pr[it][d] = fmaf(bf2f(a_t[s * 136 + i]), va[mt][it][reg], pr[it][d]);
                }
            }
        }
        #pragma unroll
        for (int it = 0; it < 2; ++it)
            #pragma unroll
            for (int d = 0; d < 3; ++d) {
                float v = pr[it][d];
                v += __shfl_xor(v, 16);
                v += __shfl_xor(v, 32);
                if (quad == 0) s_scr[(wb + it * 16 + lq) * 3 + d] = v;
            }
    }
    __syncthreads();

    // write out: out[b][i][d][n], note i*3+d == e
    for (int e = t; e < 384; e += 256)
        out[(b * 384 + e) * NN + n] = s_scr[e];
}

extern "C" void kernel_launch(void* const* d_in, const int* in_sizes, int n_in,
                              void* d_out, int out_size, void* d_ws, size_t ws_size,
                              hipStream_t stream) {
    const float* gxyz = (const float*)d_in[0];
    const float* gfts = (const float*)d_in[1];
    const float* qxyz = (const float*)d_in[2];
    const float* We1  = (const float*)d_in[3];
    const float* We2  = (const float*)d_in[4];
    const float* Wq   = (const float*)d_in[5];
    const float* Wk   = (const float*)d_in[6];
    const float* Wv   = (const float*)d_in[7];
    const float* Wr1  = (const float*)d_in[8];
    const float* Wr2  = (const float*)d_in[9];
    const float* Wstd = (const float*)d_in[10];
    const float* bf1  = (const float*)d_in[12];
    const float* bf2  = (const float*)d_in[14];
    float* out = (float*)d_out;
    float* ws  = (float*)d_ws;

    (void)hipFuncSetAttribute((const void*)fused_main,
                              hipFuncAttributeMaxDynamicSharedMemorySize, SMEM_BYTES);

    prep1<<<32, 256, 0, stream>>>(We1, We2, ws);
    prep2<<<353, 256, 0, stream>>>(Wq, Wk, Wv, Wr1, Wr2,
                                   (const float*)d_in[11], (const float*)d_in[13], ws);
    fused_main<<<BB * NN, 256, SMEM_BYTES, stream>>>(gxyz, gfts, qxyz, Wstd,
                                                     bf1, bf2, ws, out);
}

// Round 9
// 188.945 us; speedup vs baseline: 9.5110x; 1.0085x over previous
//
#include <hip/hip_runtime.h>
#include <hip/hip_bf16.h>
#include <math.h>

typedef __hip_bfloat16  bf16;
typedef __hip_bfloat162 bf162;
typedef __attribute__((ext_vector_type(8))) short short8;   // 8 bf16 (MFMA A/B frag)
typedef __attribute__((ext_vector_type(4))) float f32x4;    // MFMA C/D frag

#define BB   2
#define CINC 64
#define NN   1024
#define SSS  32
#define NS   (NN * SSS)

// ---- workspace layout (float offsets) ----
#define OFF_QT   0        // f32 [c=64][i=128]  (Phase A2)
#define OFF_WR   8192     // f32 [128]
#define OFF_WE21 8320     // f32 [o=128][c=64]
#define OFF_KB   16512    // bf16 [i=128][c=64] (Phase B B-frags)
#define OFF_VB   20608    // bf16 [i=128][c=64]
#define OFF_F1B  24704    // bf16 [o=128][kappa=384], kappa=kk*128+i
#define OFF_F2B  49280    // bf16 [o=128][c=128]
#define WS_NEED_FLOATS 57472

// ---- shared memory (BYTE offsets) ----
// att_t bf16[j*32+s][stride 136]; h_t/a_t alias in post-E.
// fts_b bf16[m=96][stride 72] dies after Phase B -> s_scr (z0/red) aliases in.
// q/xyz stored as bf16 (consumers round to bf16 anyway).
#define S_ATT_B 0         // 26112 B
#define S_FTS_B 26112     // 13824 B ; S_SCR aliases here post-B (f32[384])
#define S_SCR_B 26112
#define S_Q_B   39936     // bf16[128*3] = 768 B
#define S_XYZ_B 40704     // bf16[96] = 192 B
#define SMEM_BYTES 40896  // <= 40960 -> 4 blocks/CU

__device__ __forceinline__ float bf2f(short s) {
    unsigned int u = ((unsigned int)(unsigned short)s) << 16;
    return __uint_as_float(u);
}
__device__ __forceinline__ short f2bf(float f) {
    bf16 h = __float2bfloat16(f);
    return *reinterpret_cast<short*>(&h);
}
__device__ __forceinline__ unsigned pk2(float a, float b) {
    bf162 p = __float22bfloat162_rn(make_float2(a, b));
    return *reinterpret_cast<unsigned*>(&p);
}

// ---------- prep kernel 1: We21 = W_e2 @ W_e1 ----------
__global__ __launch_bounds__(256) void prep1(const float* __restrict__ We1,
                                             const float* __restrict__ We2,
                                             float* __restrict__ ws) {
    int e = blockIdx.x * 256 + threadIdx.x;   // 8192 entries, grid = 32
    int o = e >> 6, c = e & 63;
    float acc = 0.f;
    for (int m = 0; m < 128; ++m)
        acc = fmaf(We2[o * 128 + m], We1[m * 64 + c], acc);
    ws[OFF_WE21 + o * 64 + c] = acc;
}

// ---------- prep kernel 2: fused weights (QT f32; KB/VB/F1B/F2B bf16) ----------
__global__ __launch_bounds__(256) void prep2(const float* __restrict__ Wq,
                                             const float* __restrict__ Wk,
                                             const float* __restrict__ Wv,
                                             const float* __restrict__ Wr1,
                                             const float* __restrict__ Wr2,
                                             const float* __restrict__ Wf1,
                                             const float* __restrict__ Wf2,
                                             float* __restrict__ ws) {
    const float* we21 = ws + OFF_WE21;
    int e = blockIdx.x * 256 + threadIdx.x;
    if (e < 8192) {                            // QT f32 [c][i]
        int i = e >> 6, c = e & 63;
        float acc = 0.f;
        for (int o = 0; o < 128; ++o)
            acc = fmaf(Wq[i * 128 + o], we21[o * 64 + c], acc);
        ws[OFF_QT + c * 128 + i] = acc;
    } else if (e < 24576) {                    // KB / VB bf16 [i][c]
        int le = e - 8192;
        const float* W = (le < 8192) ? Wk : Wv;
        bf16* dst = (bf16*)(ws + ((le < 8192) ? OFF_KB : OFF_VB));
        int li = le & 8191;
        int i = li >> 6, c = li & 63;
        float acc = 0.f;
        for (int o = 0; o < 128; ++o)
            acc = fmaf(W[i * 128 + o], we21[o * 64 + c], acc);
        dst[i * 64 + c] = __float2bfloat16(acc);
    } else if (e < 24704) {                    // w_r f32
        int i = e - 24576;
        float acc = 0.f;
        for (int m = 0; m < 64; ++m)
            acc = fmaf(Wr2[i * 64 + m], Wr1[m], acc);
        ws[OFF_WR + i] = acc;
    } else if (e < 24704 + 49152) {            // F1B[o][kappa], kappa = kk*128+i
        int f = e - 24704;
        int o = f / 384, kp = f - o * 384;
        int c = (kp & 127) * 3 + (kp >> 7);
        ((bf16*)(ws + OFF_F1B))[f] = __float2bfloat16(Wf1[o * 384 + c]);
    } else if (e < 24704 + 49152 + 16384) {    // F2B[o][c]
        int f = e - (24704 + 49152);
        ((bf16*)(ws + OFF_F2B))[f] = __float2bfloat16(Wf2[f]);
    }
}

// ---------- main fused kernel: one block per (b, n), 4 blocks/CU ----------
// (256,2): VGPR cap 128 (compiler budget ~256/min_waves). R8 measured 84.
__global__ __launch_bounds__(256, 2) void fused_main(
        const float* __restrict__ gxyz, const float* __restrict__ gfts,
        const float* __restrict__ qxyz, const float* __restrict__ Wstd,
        const float* __restrict__ bf1,  const float* __restrict__ bf2,
        const float* __restrict__ ws,   float* __restrict__ out) {
    extern __shared__ char smc[];
    short* s_att  = (short*)(smc + S_ATT_B);   // att_t[(kk*32+s)][136]
    short* h_t    = s_att;                     // alias [32][136] (post-E)
    short* a_t    = s_att + 4352;              // alias [32][136]
    short* fts_s  = (short*)(smc + S_FTS_B);   // fts_b[m][72] (dies after B)
    float* s_scr  = (float*)(smc + S_SCR_B);   // alias into fts: z0 (C/D), red (H)
    short* s_qh   = (short*)(smc + S_Q_B);     // bf16 q[i][3]
    short* s_xyzh = (short*)(smc + S_XYZ_B);   // bf16 xyz_rel[96]

    const int t    = threadIdx.x;
    const int bid  = blockIdx.x;
    const int b    = bid >> 10;
    const int n    = bid & 1023;
    const int w    = t >> 6;        // wave id 0..3
    const int lane = t & 63;
    const int quad = lane >> 4;
    const int lq   = lane & 15;
    const int wb   = 32 * w;        // wave's i-base (B,H) / o-base (E,F)

    const float* gb = gfts + (size_t)b * (CINC * 3 * NS) + n * SSS;

    // ---------- Phase A: stage fts_b (bf16, transposed) + xyz_rel ----------
    for (int l4 = t; l4 < 1536; l4 += 256) {       // 6 iters, coalesced float4
        int c  = l4 / 24;
        int m4 = (l4 - c * 24) * 4;                // 0,4,...,92
        int d  = m4 >> 5, s = m4 & 31;
        float4 f = *(const float4*)(gb + (c * 3 + d) * NS + s);
        fts_s[(m4 + 0) * 72 + c] = f2bf(f.x);
        fts_s[(m4 + 1) * 72 + c] = f2bf(f.y);
        fts_s[(m4 + 2) * 72 + c] = f2bf(f.z);
        fts_s[(m4 + 3) * 72 + c] = f2bf(f.w);
    }
    if (t >= 160) {
        int id = t - 160;                // 0..95
        int d = id >> 5, s = id & 31;
        s_xyzh[id] = f2bf(gxyz[((b * NN + n) * SSS + s) * 3 + d]
                          - qxyz[(b * NN + n) * 3 + d]);
    }
    __syncthreads();

    // ---------- Phase A2: q[i][d] from fts_b rows m=0/32/64 (broadcast reads) ----------
    if (t < 128) {
        const float* qtw = ws + OFF_QT;
        float q0 = 0.f, q1 = 0.f, q2 = 0.f;
        for (int c = 0; c < 64; ++c) {
            float wq = qtw[c * 128 + t];
            q0 = fmaf(wq, bf2f(fts_s[c]),           q0);
            q1 = fmaf(wq, bf2f(fts_s[32 * 72 + c]), q1);
            q2 = fmaf(wq, bf2f(fts_s[64 * 72 + c]), q2);
        }
        s_qh[t * 3 + 0] = f2bf(q0);
        s_qh[t * 3 + 1] = f2bf(q1);
        s_qh[t * 3 + 2] = f2bf(q2);
    }
    __syncthreads();

    // ---------- Phase B (MFMA): k,v GEMMs  D[m][i] = fts[m][c]·W[i][c] ----------
    f32x4 va[6][2];   // v' = v + pos, C-layout, persists to Phase H
    {
        const short* kb = (const short*)(ws + OFF_KB);
        const short* vb = (const short*)(ws + OFF_VB);
        short8 Bk[2][2], Bv[2][2];
        #pragma unroll
        for (int it = 0; it < 2; ++it) {
            int irow = (wb + it * 16 + lq) * 64 + quad * 8;
            Bk[it][0] = *(const short8*)(kb + irow);
            Bk[it][1] = *(const short8*)(kb + irow + 32);
            Bv[it][0] = *(const short8*)(vb + irow);
            Bv[it][1] = *(const short8*)(vb + irow + 32);
        }
        float wr2[2] = { ws[OFF_WR + wb + lq], ws[OFF_WR + wb + 16 + lq] };
        #pragma unroll
        for (int mt = 0; mt < 6; ++mt) {
            const short* ap = fts_s + (mt * 16 + lq) * 72 + quad * 8;
            short8 A0 = *(const short8*)(ap);
            short8 A1 = *(const short8*)(ap + 32);
            int d = mt >> 1;
            #pragma unroll
            for (int it = 0; it < 2; ++it) {
                f32x4 kk = {0.f, 0.f, 0.f, 0.f};
                kk = __builtin_amdgcn_mfma_f32_16x16x32_bf16(A0, Bk[it][0], kk, 0, 0, 0);
                kk = __builtin_amdgcn_mfma_f32_16x16x32_bf16(A1, Bk[it][1], kk, 0, 0, 0);
                f32x4 vv = {0.f, 0.f, 0.f, 0.f};
                vv = __builtin_amdgcn_mfma_f32_16x16x32_bf16(A0, Bv[it][0], vv, 0, 0, 0);
                vv = __builtin_amdgcn_mfma_f32_16x16x32_bf16(A1, Bv[it][1], vv, 0, 0, 0);
                int i = wb + it * 16 + lq;
                float qd = bf2f(s_qh[i * 3 + d]);
                #pragma unroll
                for (int reg = 0; reg < 4; ++reg) {
                    int m = mt * 16 + quad * 4 + reg;      // m = d*32+s
                    float pos = wr2[it] * bf2f(s_xyzh[m]);
                    s_att[m * 136 + i] = f2bf(qd - kk[reg] + pos);
                    va[mt][it][reg] = vv[reg] + pos;
                }
            }
        }
    }
    __syncthreads();

    // ---------- Phase C (MFMA): z0[j][rem] = sum_i Wstd[j][i]*att_t[rem][i] ----------
    // M=16 (j, rows>=3 zero-padded) N=96 (6 tiles of 16) K=128.
    {
        short8 As[4];
        #pragma unroll
        for (int kc = 0; kc < 4; ++kc) {
            short8 a = {0, 0, 0, 0, 0, 0, 0, 0};
            if (lq < 3) {
                const float* wp = Wstd + lq * 128 + kc * 32 + quad * 8;
                float4 w0 = *(const float4*)(wp);
                float4 w1 = *(const float4*)(wp + 4);
                a[0] = f2bf(w0.x); a[1] = f2bf(w0.y); a[2] = f2bf(w0.z); a[3] = f2bf(w0.w);
                a[4] = f2bf(w1.x); a[5] = f2bf(w1.y); a[6] = f2bf(w1.z); a[7] = f2bf(w1.w);
            }
            As[kc] = a;
        }
        for (int tile = w; tile < 6; tile += 4) {     // waves 0,1 take 2 tiles
            f32x4 acc = {0.f, 0.f, 0.f, 0.f};
            const short* bp = s_att + (tile * 16 + lq) * 136 + quad * 8;
            #pragma unroll
            for (int kc = 0; kc < 4; ++kc) {
                short8 bfr = *(const short8*)(bp + kc * 32);
                acc = __builtin_amdgcn_mfma_f32_16x16x32_bf16(As[kc], bfr, acc, 0, 0, 0);
            }
            if (quad == 0) {          // rows 0..2 = j ; z0: j*96 + rem
                #pragma unroll
                for (int reg = 0; reg < 3; ++reg)
                    s_scr[reg * 96 + tile * 16 + lq] = acc[reg];
            }
        }
    }
    __syncthreads();

    // ---------- Phase D: attn2[i][kk][s] = sum_j attn[i][j][s]*z0[j][kk][s] (in place) ----------
    for (int u = t; u < 512; u += 256) {
        int s  = u >> 4;
        int i0 = (u & 15) * 8;
        float z[3][3];
        #pragma unroll
        for (int j = 0; j < 3; ++j)
            #pragma unroll
            for (int kk = 0; kk < 3; ++kk)
                z[j][kk] = s_scr[j * 96 + kk * 32 + s];
        float af[3][8];
        #pragma unroll
        for (int j = 0; j < 3; ++j) {
            short8 v8 = *(const short8*)(s_att + (j * 32 + s) * 136 + i0);
            #pragma unroll
            for (int x = 0; x < 8; ++x) af[j][x] = bf2f(v8[x]);
        }
        #pragma unroll
        for (int kk = 0; kk < 3; ++kk) {
            short8 o8;
            #pragma unroll
            for (int x = 0; x < 8; ++x)
                o8[x] = f2bf(af[0][x] * z[0][kk] + af[1][x] * z[1][kk] + af[2][x] * z[2][kk]);
            *(short8*)(s_att + (kk * 32 + s) * 136 + i0) = o8;
        }
    }
    __syncthreads();

    // ---------- Phase E: h = relu(Wf1 @ attn2 + b_f1) via MFMA (M=128,N=32,K=384) ----------
    f32x4 eacc[2][2];
    {
        f32x4 zz = {0.f, 0.f, 0.f, 0.f};
        eacc[0][0] = zz; eacc[0][1] = zz; eacc[1][0] = zz; eacc[1][1] = zz;
        const short* f1b = (const short*)(ws + OFF_F1B);
        const short* ab0 = f1b + (wb + lq) * 384 + quad * 8;
        const short* ab1 = ab0 + 16 * 384;
        #pragma unroll 2
        for (int ks = 0; ks < 12; ++ks) {
            int kk = ks >> 2;
            int ic = (ks & 3) * 32 + quad * 8;
            short8 a0 = *(const short8*)(ab0 + ks * 32);
            short8 a1 = *(const short8*)(ab1 + ks * 32);
            const short* bp = s_att + (kk * 32) * 136 + ic;
            short8 b0 = *(const short8*)(bp + lq * 136);
            short8 b1 = *(const short8*)(bp + (lq + 16) * 136);
            eacc[0][0] = __builtin_amdgcn_mfma_f32_16x16x32_bf16(a0, b0, eacc[0][0], 0, 0, 0);
            eacc[0][1] = __builtin_amdgcn_mfma_f32_16x16x32_bf16(a0, b1, eacc[0][1], 0, 0, 0);
            eacc[1][0] = __builtin_amdgcn_mfma_f32_16x16x32_bf16(a1, b0, eacc[1][0], 0, 0, 0);
            eacc[1][1] = __builtin_amdgcn_mfma_f32_16x16x32_bf16(a1, b1, eacc[1][1], 0, 0, 0);
        }
    }
    __syncthreads();     // all att_t reads complete before h_t overwrites it

    // E epilogue: h_t[s][o] (bf16), relu+bias
    #pragma unroll
    for (int mt = 0; mt < 2; ++mt) {
        int ob = wb + mt * 16 + quad * 4;
        float4 bb = *(const float4*)(bf1 + ob);
        float bv[4] = {bb.x, bb.y, bb.z, bb.w};
        #pragma unroll
        for (int nt = 0; nt < 2; ++nt) {
            f32x4 c = eacc[mt][nt];
            int s = nt * 16 + lq;
            uint2 pk;
            pk.x = pk2(fmaxf(c[0] + bv[0], 0.f), fmaxf(c[1] + bv[1], 0.f));
            pk.y = pk2(fmaxf(c[2] + bv[2], 0.f), fmaxf(c[3] + bv[3], 0.f));
            *(uint2*)(h_t + s * 136 + ob) = pk;
        }
    }
    __syncthreads();

    // ---------- Phase F: logits = Wf2 @ h + b_f2 via MFMA (M=128,N=32,K=128) ----------
    {
        f32x4 facc[2][2];
        f32x4 zz = {0.f, 0.f, 0.f, 0.f};
        facc[0][0] = zz; facc[0][1] = zz; facc[1][0] = zz; facc[1][1] = zz;
        const short* f2b = (const short*)(ws + OFF_F2B);
        const short* ab0 = f2b + (wb + lq) * 128 + quad * 8;
        const short* ab1 = ab0 + 16 * 128;
        #pragma unroll 2
        for (int ks = 0; ks < 4; ++ks) {
            int c0 = ks * 32 + quad * 8;
            short8 a0 = *(const short8*)(ab0 + ks * 32);
            short8 a1 = *(const short8*)(ab1 + ks * 32);
            short8 b0 = *(const short8*)(h_t + lq * 136 + c0);
            short8 b1 = *(const short8*)(h_t + (lq + 16) * 136 + c0);
            facc[0][0] = __builtin_amdgcn_mfma_f32_16x16x32_bf16(a0, b0, facc[0][0], 0, 0, 0);
            facc[0][1] = __builtin_amdgcn_mfma_f32_16x16x32_bf16(a0, b1, facc[0][1], 0, 0, 0);
            facc[1][0] = __builtin_amdgcn_mfma_f32_16x16x32_bf16(a1, b0, facc[1][0], 0, 0, 0);
            facc[1][1] = __builtin_amdgcn_mfma_f32_16x16x32_bf16(a1, b1, facc[1][1], 0, 0, 0);
        }
        // a_t region disjoint from h_t; att_t dead -> no barrier before stores
        #pragma unroll
        for (int mt = 0; mt < 2; ++mt) {
            int ob = wb + mt * 16 + quad * 4;
            float4 bb = *(const float4*)(bf2 + ob);
            float bv[4] = {bb.x, bb.y, bb.z, bb.w};
            #pragma unroll
            for (int nt = 0; nt < 2; ++nt) {
                f32x4 c = facc[mt][nt];
                int s = nt * 16 + lq;
                uint2 pk;
                pk.x = pk2(c[0] + bv[0], c[1] + bv[1]);
                pk.y = pk2(c[2] + bv[2], c[3] + bv[3]);
                *(uint2*)(a_t + s * 136 + ob) = pk;
            }
        }
    }
    __syncthreads();

    // ---------- Phase G: softmax over s (scale 1/sqrt(128)), a_t[s][i] ----------
    if (t < 128) {
        float vals[32];
        #pragma unroll
        for (int s = 0; s < 32; ++s) vals[s] = bf2f(a_t[s * 136 + t]);
        float mx = -INFINITY;
        #pragma unroll
        for (int s = 0; s < 32; ++s) mx = fmaxf(mx, vals[s]);
        const float inv = 0.08838834764831845f;   // 1/sqrt(128)
        float sum = 0.f;
        #pragma unroll
        for (int s = 0; s < 32; ++s) { vals[s] = __expf((vals[s] - mx) * inv); sum += vals[s]; }
        float rs = 1.f / sum;
        #pragma unroll
        for (int s = 0; s < 32; ++s) a_t[s * 136 + t] = f2bf(vals[s] * rs);
    }
    __syncthreads();

    // ---------- Phase H: resi[i][d] = sum_s a[s][i] * v'[i][m=d*32+s] ----------
    {
        float pr[2][3];
        #pragma unroll
        for (int it = 0; it < 2; ++it)
            #pragma unroll
            for (int d = 0; d < 3; ++d) pr[it][d] = 0.f;
        #pragma unroll
        for (int mt = 0; mt < 6; ++mt) {
            int d = mt >> 1;
            #pragma unroll
            for (int it = 0; it < 2; ++it) {
                int i = wb + it * 16 + lq;
                #pragma unroll
                for (int reg = 0; reg < 4; ++reg) {
                    int s = (mt & 1) * 16 + quad * 4 + reg;
                    pr[it][d] = fmaf(bf2f(a_t[s * 136 + i]), va[mt][it][reg], pr[it][d]);
                }
            }
        }
        #pragma unroll
        for (int it = 0; it < 2; ++it)
            #pragma unroll
            for (int d = 0; d < 3; ++d) {
                float v = pr[it][d];
                v += __shfl_xor(v, 16);
                v += __shfl_xor(v, 32);
                if (quad == 0) s_scr[(wb + it * 16 + lq) * 3 + d] = v;
            }
    }
    __syncthreads();

    // write out: out[b][i][d][n], note i*3+d == e
    for (int e = t; e < 384; e += 256)
        out[(b * 384 + e) * NN + n] = s_scr[e];
}

extern "C" void kernel_launch(void* const* d_in, const int* in_sizes, int n_in,
                              void* d_out, int out_size, void* d_ws, size_t ws_size,
                              hipStream_t stream) {
    const float* gxyz = (const float*)d_in[0];
    const float* gfts = (const float*)d_in[1];
    const float* qxyz = (const float*)d_in[2];
    const float* We1  = (const float*)d_in[3];
    const float* We2  = (const float*)d_in[4];
    const float* Wq   = (const float*)d_in[5];
    const float* Wk   = (const float*)d_in[6];
    const float* Wv   = (const float*)d_in[7];
    const float* Wr1  = (const float*)d_in[8];
    const float* Wr2  = (const float*)d_in[9];
    const float* Wstd = (const float*)d_in[10];
    const float* bf1  = (const float*)d_in[12];
    const float* bf2  = (const float*)d_in[14];
    float* out = (float*)d_out;
    float* ws  = (float*)d_ws;

    (void)hipFuncSetAttribute((const void*)fused_main,
                              hipFuncAttributeMaxDynamicSharedMemorySize, SMEM_BYTES);

    prep1<<<32, 256, 0, stream>>>(We1, We2, ws);
    prep2<<<353, 256, 0, stream>>>(Wq, Wk, Wv, Wr1, Wr2,
                                   (const float*)d_in[11], (const float*)d_in[13], ws);
    fused_main<<<BB * NN, 256, SMEM_BYTES, stream>>>(gxyz, gfts, qxyz, Wstd,
                                                     bf1, bf2, ws, out);
}